// Round 1
// baseline (793.206 us; speedup 1.0000x reference)
//
#include <hip/hip_runtime.h>
#include <math.h>

#define S_LEN 8192
#define NB 4
#define EMB 256
#define NH 8
#define DKK 64
#define DVV 32
#define WINW 65
#define NEGV (-1e9f)
#define BSROWS (NB * S_LEN)

// ---------------------------------------------------------------------------
// GEMM: C[M,N] = A[M,256] @ W[256,N] + bias, optional ReLU.
// BM=BN=128, BK=16, 256 threads, 8x8 microtile per thread.
// ---------------------------------------------------------------------------
template<bool RELU>
__global__ __launch_bounds__(256, 2)
void gemm_k256(const float* __restrict__ A, const float* __restrict__ W,
               const float* __restrict__ bias, float* __restrict__ C, int N)
{
    __shared__ float As[16][128];   // k-major (transposed A tile)
    __shared__ float Ws[16][128];

    const int t = threadIdx.x;
    const int tm = t >> 4;          // 0..15
    const int tn = t & 15;          // 0..15
    const int rbase = blockIdx.y * 128;
    const int cbase = blockIdx.x * 128;

    float acc[8][8];
#pragma unroll
    for (int i = 0; i < 8; ++i)
#pragma unroll
        for (int j = 0; j < 8; ++j) acc[i][j] = 0.f;

    const int ar = t >> 2;          // 0..63
    const int ak = (t & 3) << 2;    // 0,4,8,12
    const int wc = (t & 31) << 2;   // 0..124
    const int wk = t >> 5;          // 0..7

    for (int k0 = 0; k0 < 256; k0 += 16) {
#pragma unroll
        for (int p = 0; p < 2; ++p) {
            const int r = ar + p * 64;
            const float4 a = *reinterpret_cast<const float4*>(
                &A[(size_t)(rbase + r) * 256 + k0 + ak]);
            As[ak + 0][r] = a.x; As[ak + 1][r] = a.y;
            As[ak + 2][r] = a.z; As[ak + 3][r] = a.w;
        }
#pragma unroll
        for (int p = 0; p < 2; ++p) {
            const int kr = wk + p * 8;
            *reinterpret_cast<float4*>(&Ws[kr][wc]) =
                *reinterpret_cast<const float4*>(&W[(size_t)(k0 + kr) * N + cbase + wc]);
        }
        __syncthreads();
#pragma unroll
        for (int kk = 0; kk < 16; ++kk) {
            const float4 a0 = *reinterpret_cast<const float4*>(&As[kk][tm * 4]);
            const float4 a1 = *reinterpret_cast<const float4*>(&As[kk][tm * 4 + 64]);
            const float4 w0 = *reinterpret_cast<const float4*>(&Ws[kk][tn * 4]);
            const float4 w1 = *reinterpret_cast<const float4*>(&Ws[kk][tn * 4 + 64]);
            const float av[8] = {a0.x, a0.y, a0.z, a0.w, a1.x, a1.y, a1.z, a1.w};
            const float wv[8] = {w0.x, w0.y, w0.z, w0.w, w1.x, w1.y, w1.z, w1.w};
#pragma unroll
            for (int i = 0; i < 8; ++i)
#pragma unroll
                for (int j = 0; j < 8; ++j)
                    acc[i][j] = fmaf(av[i], wv[j], acc[i][j]);
        }
        __syncthreads();
    }

    const float4 b0 = *reinterpret_cast<const float4*>(&bias[cbase + tn * 4]);
    const float4 b1 = *reinterpret_cast<const float4*>(&bias[cbase + tn * 4 + 64]);
    const float bb[8] = {b0.x, b0.y, b0.z, b0.w, b1.x, b1.y, b1.z, b1.w};

#pragma unroll
    for (int i = 0; i < 8; ++i) {
        const int row = rbase + tm * 4 + (i & 3) + (i >> 2) * 64;
        float vals[8];
#pragma unroll
        for (int j = 0; j < 8; ++j) {
            float vv = acc[i][j] + bb[j];
            if (RELU) vv = fmaxf(vv, 0.f);
            vals[j] = vv;
        }
        *reinterpret_cast<float4*>(&C[(size_t)row * N + cbase + tn * 4]) =
            make_float4(vals[0], vals[1], vals[2], vals[3]);
        *reinterpret_cast<float4*>(&C[(size_t)row * N + cbase + tn * 4 + 64]) =
            make_float4(vals[4], vals[5], vals[6], vals[7]);
    }
}

// ---------------------------------------------------------------------------
// Banded local attention. Grid: (S/64, B*H). Block: 256 = 4 waves.
// Wave handles 16 queries sequentially; per query: lane w in [0,64) computes
// window-w score; window 64 via cross-lane reduce; shuffle softmax; PV with
// even/odd window split across lane halves.
// ---------------------------------------------------------------------------
__global__ __launch_bounds__(256, 2)
void attn_local(const float* __restrict__ qb, const float* __restrict__ kb,
                const float* __restrict__ vb, const float* __restrict__ rb,
                float* __restrict__ ob)
{
    __shared__ float Ks[128][68];   // rows i0-32 .. i0+95, padded stride 68
    __shared__ float Vs[128][32];
    __shared__ float Qs[64][68];

    const int t = threadIdx.x;
    const int bh = blockIdx.y;
    const int b = bh >> 3, h = bh & 7;
    const int i0 = blockIdx.x * 64;

    // --- stage K (zero-fill out-of-range rows)
    for (int idx = t; idx < 128 * 16; idx += 256) {
        const int r = idx >> 4;
        const int d = (idx & 15) << 2;
        const int pos = i0 - 32 + r;
        float4 kv = make_float4(0.f, 0.f, 0.f, 0.f);
        if (pos >= 0 && pos < S_LEN)
            kv = *reinterpret_cast<const float4*>(
                &kb[((size_t)b * S_LEN + pos) * 512 + h * 64 + d]);
        *reinterpret_cast<float4*>(&Ks[r][d]) = kv;
    }
    // --- stage V
    for (int idx = t; idx < 128 * 8; idx += 256) {
        const int r = idx >> 3;
        const int d = (idx & 7) << 2;
        const int pos = i0 - 32 + r;
        float4 vv = make_float4(0.f, 0.f, 0.f, 0.f);
        if (pos >= 0 && pos < S_LEN)
            vv = *reinterpret_cast<const float4*>(
                &vb[((size_t)b * S_LEN + pos) * 256 + h * 32 + d]);
        *reinterpret_cast<float4*>(&Vs[r][d]) = vv;
    }
    // --- stage Q
    for (int idx = t; idx < 64 * 16; idx += 256) {
        const int r = idx >> 4;
        const int d = (idx & 15) << 2;
        const float4 qv = *reinterpret_cast<const float4*>(
            &qb[((size_t)b * S_LEN + i0 + r) * 512 + h * 64 + d]);
        *reinterpret_cast<float4*>(&Qs[r][d]) = qv;
    }
    __syncthreads();

    const int wave = t >> 6, lane = t & 63;
    const float rbl = rb[h * WINW + lane];     // bias for w = lane
    const float rb64 = rb[h * WINW + 64];
    const int dv = lane & 31, half = lane >> 5;

    for (int qi = 0; qi < 16; ++qi) {
        const int qoff = wave * 16 + qi;
        const int i = i0 + qoff;

        // scores: window w = lane -> key row (qoff + lane)
        float s = 0.f;
        const float* krow = Ks[qoff + lane];
        const float* qrow = Qs[qoff];
#pragma unroll
        for (int d4 = 0; d4 < 16; ++d4) {
            const float4 kv = *reinterpret_cast<const float4*>(&krow[d4 * 4]);
            const float4 qv = *reinterpret_cast<const float4*>(&qrow[d4 * 4]);
            s = fmaf(qv.x, kv.x, s); s = fmaf(qv.y, kv.y, s);
            s = fmaf(qv.z, kv.z, s); s = fmaf(qv.w, kv.w, s);
        }
        // window 64: distribute dot over lanes, butterfly-reduce
        float s64 = Qs[qoff][lane] * Ks[qoff + 64][lane];
#pragma unroll
        for (int off = 32; off; off >>= 1) s64 += __shfl_xor(s64, off);

        const int kpos = i - 32 + lane;
        float sc = (kpos >= 0 && kpos < S_LEN) ? fmaf(s, 0.125f, rbl) : NEGV;
        const float sc64 = (i + 32 < S_LEN) ? fmaf(s64, 0.125f, rb64) : NEGV;

        // softmax over 65 entries (64 lane-held + sc64 known to all)
        float m = sc;
#pragma unroll
        for (int off = 32; off; off >>= 1) m = fmaxf(m, __shfl_xor(m, off));
        m = fmaxf(m, sc64);
        const float e = __expf(sc - m);
        const float e64 = __expf(sc64 - m);
        float sum = e;
#pragma unroll
        for (int off = 32; off; off >>= 1) sum += __shfl_xor(sum, off);
        sum += e64;
        const float inv = 1.f / sum;

        // PV: lane = half*32 + dv; half 0 takes even windows, half 1 odd.
        float o = 0.f;
#pragma unroll
        for (int w2 = 0; w2 < 32; ++w2) {
            const int w = w2 * 2 + half;
            const float pw = __shfl(e, w);
            o = fmaf(pw, Vs[qoff + w][dv], o);
        }
        if (half == 0) o = fmaf(e64, Vs[qoff + 64][dv], o);
        o += __shfl_xor(o, 32);
        if (half == 0)
            ob[((size_t)b * S_LEN + i) * 256 + h * 32 + dv] = o * inv;
    }
}

// ---------------------------------------------------------------------------
// out = LayerNorm(a + r) * g + b   (row length 256; one wave per row)
// ---------------------------------------------------------------------------
__global__ __launch_bounds__(256, 4)
void add_ln(const float* __restrict__ a, const float* __restrict__ r,
            const float* __restrict__ g, const float* __restrict__ be,
            float* __restrict__ o)
{
    const int row = blockIdx.x * 4 + (threadIdx.x >> 6);
    const int lane = threadIdx.x & 63;
    const size_t base = (size_t)row * 256 + lane * 4;

    const float4 va = *reinterpret_cast<const float4*>(&a[base]);
    const float4 vr = *reinterpret_cast<const float4*>(&r[base]);
    const float v0 = va.x + vr.x, v1 = va.y + vr.y;
    const float v2 = va.z + vr.z, v3 = va.w + vr.w;

    float sum = v0 + v1 + v2 + v3;
#pragma unroll
    for (int off = 32; off; off >>= 1) sum += __shfl_xor(sum, off);
    const float mean = sum * (1.f / 256.f);

    const float d0 = v0 - mean, d1 = v1 - mean, d2 = v2 - mean, d3 = v3 - mean;
    float ss = d0 * d0 + d1 * d1 + d2 * d2 + d3 * d3;
#pragma unroll
    for (int off = 32; off; off >>= 1) ss += __shfl_xor(ss, off);
    const float rs = rsqrtf(ss * (1.f / 256.f) + 1e-5f);

    const float4 vg = *reinterpret_cast<const float4*>(&g[lane * 4]);
    const float4 vb = *reinterpret_cast<const float4*>(&be[lane * 4]);
    float4 out;
    out.x = d0 * rs * vg.x + vb.x;
    out.y = d1 * rs * vg.y + vb.y;
    out.z = d2 * rs * vg.z + vb.z;
    out.w = d3 * rs * vg.w + vb.w;
    *reinterpret_cast<float4*>(&o[base]) = out;
}

// ---------------------------------------------------------------------------
extern "C" void kernel_launch(void* const* d_in, const int* in_sizes, int n_in,
                              void* d_out, int out_size, void* d_ws, size_t ws_size,
                              hipStream_t stream)
{
    const float* x   = (const float*)d_in[0];
    const float* Wq  = (const float*)d_in[1];
    const float* bq  = (const float*)d_in[2];
    const float* Wk  = (const float*)d_in[3];
    const float* bk  = (const float*)d_in[4];
    const float* Wv  = (const float*)d_in[5];
    const float* bv  = (const float*)d_in[6];
    const float* Wo  = (const float*)d_in[7];
    const float* bo  = (const float*)d_in[8];
    const float* rel = (const float*)d_in[9];
    const float* g1  = (const float*)d_in[10];
    const float* b1  = (const float*)d_in[11];
    const float* Wl  = (const float*)d_in[12];
    const float* bl  = (const float*)d_in[13];
    const float* g2  = (const float*)d_in[14];
    const float* b2  = (const float*)d_in[15];
    float* out = (float*)d_out;

    float* q    = (float*)d_ws;                       // [BS][512]
    float* kbuf = q    + (size_t)BSROWS * 512;        // [BS][512]
    float* vbuf = kbuf + (size_t)BSROWS * 512;        // [BS][256]
    float* attn = vbuf + (size_t)BSROWS * 256;        // [BS][256]
    float* tmp  = q;      // reuse q region after attention
    float* xs   = kbuf;   // reuse k region
    float* lin  = vbuf;   // reuse v region

    dim3 blk(256);
    gemm_k256<false><<<dim3(4, BSROWS / 128), blk, 0, stream>>>(x, Wq, bq, q, 512);
    gemm_k256<false><<<dim3(4, BSROWS / 128), blk, 0, stream>>>(x, Wk, bk, kbuf, 512);
    gemm_k256<false><<<dim3(2, BSROWS / 128), blk, 0, stream>>>(x, Wv, bv, vbuf, 256);

    attn_local<<<dim3(S_LEN / 64, NB * NH), blk, 0, stream>>>(q, kbuf, vbuf, rel, attn);

    gemm_k256<false><<<dim3(2, BSROWS / 128), blk, 0, stream>>>(attn, Wo, bo, tmp, 256);
    add_ln<<<dim3(BSROWS / 4), blk, 0, stream>>>(tmp, x, g1, b1, xs);
    gemm_k256<true ><<<dim3(2, BSROWS / 128), blk, 0, stream>>>(xs, Wl, bl, lin, 256);
    add_ln<<<dim3(BSROWS / 4), blk, 0, stream>>>(lin, xs, g2, b2, out);
}

// Round 9
// 258.648 us; speedup vs baseline: 3.0667x; 3.0667x over previous
//
#include <hip/hip_runtime.h>
#include <math.h>

#define S_LEN 8192
#define NB 4
#define NH 8
#define BSROWS (NB * S_LEN)

typedef __bf16 bf16x8 __attribute__((ext_vector_type(8)));
typedef float f32x4 __attribute__((ext_vector_type(4)));
typedef unsigned short u16;
typedef const __attribute__((address_space(1))) void* as1cv;
typedef __attribute__((address_space(3))) void* as3v;

__device__ __forceinline__ u16 f2bf(float f) {
    union { float f; unsigned int u; } v; v.f = f;
    unsigned int r = v.u + 0x7FFFu + ((v.u >> 16) & 1u);
    return (u16)(r >> 16);
}

__device__ __forceinline__ void gload16(const void* g, void* l) {
    __builtin_amdgcn_global_load_lds((as1cv)g, (as3v)l, 16, 0, 0);
}

__device__ __forceinline__ bf16x8 lds_b8(const u16* base, int byteoff) {
    return *reinterpret_cast<const bf16x8*>(reinterpret_cast<const char*>(base) + byteoff);
}

// ---------------------------------------------------------------------------
// bf16 MFMA GEMM: C[M,N] = A[M,256](bf16) @ W[256,N] + bias.
// Wt is pre-transposed [N][256] bf16. BM=BN=128, BK=64, 4 waves (2x2 of 64x64).
// LDS rows 128B, XOR-swizzled chunk ^ (row&7); staged via global_load_lds w=16.
// ---------------------------------------------------------------------------
template<bool RELU, bool BF16OUT>
__global__ __launch_bounds__(256, 2)
void gemm_bf16(const u16* __restrict__ A, const u16* __restrict__ Wt,
               const float* __restrict__ bias, void* __restrict__ Cv,
               int N, int nbx)
{
    __shared__ u16 As[128 * 64];
    __shared__ u16 Bs[128 * 64];

    const int t = threadIdx.x;
    const int wv = t >> 6, ln = t & 63;

    // XCD-aware swizzle (gridDim.x % 8 == 0 for all our launches)
    const int nwg = gridDim.x;
    const int qq = nwg >> 3;
    const int swz = (blockIdx.x & 7) * qq + (blockIdx.x >> 3);
    const int by = swz / nbx, bx = swz % nbx;
    const int rbase = by * 128, cbase = bx * 128;

    const int wr = wv >> 1, wc = wv & 1;
    const int frow = ln & 15, fk = ln >> 4;

    f32x4 acc[4][4];
#pragma unroll
    for (int i = 0; i < 4; ++i)
#pragma unroll
        for (int j = 0; j < 4; ++j) acc[i][j] = f32x4{0.f, 0.f, 0.f, 0.f};

    const int srow_b = (ln >> 3);        // 0..7 within wave segment
    const int scb    = ln & 7;

    for (int k0 = 0; k0 < 256; k0 += 64) {
#pragma unroll
        for (int r = 0; r < 4; ++r) {
            const int rowA = r * 32 + wv * 8 + srow_b;
            const int cbs = scb ^ (rowA & 7);
            gload16(A + (size_t)(rbase + rowA) * 256 + k0 + cbs * 8,
                    As + r * 2048 + wv * 512);
            gload16(Wt + (size_t)(cbase + rowA) * 256 + k0 + cbs * 8,
                    Bs + r * 2048 + wv * 512);
        }
        __syncthreads();

        bf16x8 af[4][2], bfr[4][2];
#pragma unroll
        for (int mi = 0; mi < 4; ++mi)
#pragma unroll
            for (int kk = 0; kk < 2; ++kk) {
                const int row = wr * 64 + mi * 16 + frow;
                const int cb = (kk * 4 + fk) ^ (row & 7);
                af[mi][kk] = lds_b8(As, row * 128 + cb * 16);
            }
#pragma unroll
        for (int ni = 0; ni < 4; ++ni)
#pragma unroll
            for (int kk = 0; kk < 2; ++kk) {
                const int row = wc * 64 + ni * 16 + frow;
                const int cb = (kk * 4 + fk) ^ (row & 7);
                bfr[ni][kk] = lds_b8(Bs, row * 128 + cb * 16);
            }
#pragma unroll
        for (int mi = 0; mi < 4; ++mi)
#pragma unroll
            for (int ni = 0; ni < 4; ++ni)
#pragma unroll
                for (int kk = 0; kk < 2; ++kk)
                    acc[mi][ni] = __builtin_amdgcn_mfma_f32_16x16x32_bf16(
                        af[mi][kk], bfr[ni][kk], acc[mi][ni], 0, 0, 0);
        __syncthreads();
    }

    float cbias[4];
#pragma unroll
    for (int ni = 0; ni < 4; ++ni)
        cbias[ni] = bias[cbase + wc * 64 + ni * 16 + frow];

#pragma unroll
    for (int mi = 0; mi < 4; ++mi) {
        const int row0 = rbase + wr * 64 + mi * 16 + fk * 4;
#pragma unroll
        for (int ni = 0; ni < 4; ++ni) {
            const int col = cbase + wc * 64 + ni * 16 + frow;
#pragma unroll
            for (int j = 0; j < 4; ++j) {
                float v = acc[mi][ni][j] + cbias[ni];
                if (RELU) v = fmaxf(v, 0.f);
                if (BF16OUT)
                    ((u16*)Cv)[(size_t)(row0 + j) * N + col] = f2bf(v);
                else
                    ((float*)Cv)[(size_t)(row0 + j) * N + col] = v;
            }
        }
    }
}

// ---------------------------------------------------------------------------
// MFMA banded attention. Grid (S/64, B*H), 256 thr = 4 waves, wave = 16 queries.
// Keys tile rows 0..127 = positions i0-32 .. i0+95. Wave wv uses key subtiles
// ni=0..4 (80 keys from wv*16). Softmax in C-layout; P->LDS bf16; PV via
// out^T = V^T @ P^T (V pre-transposed in HBM).
// Out-of-range staging positions are CLAMPED into the buffer (softmax masks
// those slots, and clamped data is finite so 0*x can't produce NaN).
// ---------------------------------------------------------------------------
__global__ __launch_bounds__(256, 3)
void attn_mfma(const u16* __restrict__ qb, const u16* __restrict__ kb,
               const u16* __restrict__ vt, const float* __restrict__ rel,
               u16* __restrict__ ob)
{
    __shared__ u16 Ks[128 * 64];    // [key][d]  swz ^(key&7)
    __shared__ u16 Qs[64 * 64];     // [q][d]    swz ^(q&7)
    __shared__ u16 Vts[32 * 128];   // [dv][key] swz ^(dv&15)
    __shared__ u16 Ps[4][16 * 104]; // per-wave P[q][key_local], stride 104
    __shared__ float rbs[72];

    const int t = threadIdx.x, wv = t >> 6, ln = t & 63;
    const int bh = blockIdx.y, b = bh >> 3, h = bh & 7;
    const int i0 = blockIdx.x * 64;

    // stage K: 128 rows x 128B (clamped into [0, S_LEN-1])
#pragma unroll
    for (int r = 0; r < 4; ++r) {
        const int row = r * 32 + wv * 8 + (ln >> 3);
        const int cbs = (ln & 7) ^ (row & 7);
        int pos = i0 - 32 + row;
        pos = pos < 0 ? 0 : (pos >= S_LEN ? S_LEN - 1 : pos);
        const long long grow = (long long)b * S_LEN + pos;
        gload16((const char*)kb + grow * 1024 + h * 128 + cbs * 16,
                Ks + r * 2048 + wv * 512);
    }
    // stage Q: 64 rows x 128B (always in range)
#pragma unroll
    for (int r = 0; r < 2; ++r) {
        const int row = r * 32 + wv * 8 + (ln >> 3);
        const int cbs = (ln & 7) ^ (row & 7);
        gload16((const char*)qb + ((size_t)(b * S_LEN + i0 + row)) * 1024 + h * 128 + cbs * 16,
                Qs + r * 2048 + wv * 512);
    }
    // stage V^T: 32 rows x 256B (byte offset clamped into the dv-row)
#pragma unroll
    for (int r = 0; r < 2; ++r) {
        const int row = r * 16 + wv * 4 + (ln >> 4);
        const int cbs = (ln & 15) ^ (row & 15);
        long long off = (long long)(i0 - 32) * 2 + cbs * 16;
        off = off < 0 ? 0 : (off > (long long)(S_LEN * 2 - 16) ? (long long)(S_LEN * 2 - 16) : off);
        gload16((const char*)vt + ((size_t)bh * 32 + row) * (S_LEN * 2) + off,
                Vts + r * 2048 + wv * 512);
    }
    if (t < 65) rbs[t] = rel[h * 65 + t];
    __syncthreads();

    const int frow = ln & 15, fk = ln >> 4, g = fk;

    // ---- scores: S = Q @ K^T
    bf16x8 aq[2];
    const int qrow = wv * 16 + frow;
#pragma unroll
    for (int kk = 0; kk < 2; ++kk) {
        const int cb = (kk * 4 + fk) ^ (qrow & 7);
        aq[kk] = lds_b8(Qs, qrow * 128 + cb * 16);
    }
    f32x4 sacc[5];
#pragma unroll
    for (int ni = 0; ni < 5; ++ni) {
        sacc[ni] = f32x4{0.f, 0.f, 0.f, 0.f};
        const int krow = wv * 16 + ni * 16 + frow;
#pragma unroll
        for (int kk = 0; kk < 2; ++kk) {
            const int cb = (kk * 4 + fk) ^ (krow & 7);
            bf16x8 bk = lds_b8(Ks, krow * 128 + cb * 16);
            sacc[ni] = __builtin_amdgcn_mfma_f32_16x16x32_bf16(aq[kk], bk, sacc[ni], 0, 0, 0);
        }
    }

    // ---- softmax (rows q = wv*16 + g*4 + j; cols key = wv*16 + ni*16 + frow)
    float p[5][4];
#pragma unroll
    for (int j = 0; j < 4; ++j) {
        const int qloc = g * 4 + j;                 // within wave tile
        const int iq = i0 + wv * 16 + qloc;         // global query
        float mx = -1e30f;
#pragma unroll
        for (int ni = 0; ni < 5; ++ni) {
            const int w = ni * 16 + frow - qloc;    // window offset
            const long long pos = (long long)iq - 32 + w;
            const bool valid = (w >= 0) & (w <= 64) & (pos >= 0) & (pos < S_LEN);
            const int wc2 = w < 0 ? 0 : (w > 64 ? 64 : w);
            const float s = valid ? fmaf(sacc[ni][j], 0.125f, rbs[wc2]) : -1e9f;
            p[ni][j] = s;
            mx = fmaxf(mx, s);
        }
        mx = fmaxf(mx, __shfl_xor(mx, 1));
        mx = fmaxf(mx, __shfl_xor(mx, 2));
        mx = fmaxf(mx, __shfl_xor(mx, 4));
        mx = fmaxf(mx, __shfl_xor(mx, 8));
        float sum = 0.f;
#pragma unroll
        for (int ni = 0; ni < 5; ++ni) {
            const float e = __expf(p[ni][j] - mx);
            p[ni][j] = e; sum += e;
        }
        sum += __shfl_xor(sum, 1);
        sum += __shfl_xor(sum, 2);
        sum += __shfl_xor(sum, 4);
        sum += __shfl_xor(sum, 8);
        const float inv = 1.f / sum;
#pragma unroll
        for (int ni = 0; ni < 5; ++ni) p[ni][j] *= inv;
    }

    // ---- P -> LDS (bf16), zero-pad key_local 80..95
    u16* Pw = &Ps[wv][0];
    {
        const int zr = ln >> 2, zc = 80 + (ln & 3) * 4;
        *reinterpret_cast<uint2*>(Pw + zr * 104 + zc) = uint2{0u, 0u};
    }
#pragma unroll
    for (int ni = 0; ni < 5; ++ni)
#pragma unroll
        for (int j = 0; j < 4; ++j)
            Pw[(g * 4 + j) * 104 + ni * 16 + frow] = f2bf(p[ni][j]);

    // barrier: P is written by one lane and read by another (cross-lane LDS
    // dep the compiler can't see). Cheap and guarantees lgkmcnt ordering.
    __syncthreads();

    // ---- PV: out^T[dv][q] = sum_key V^T[dv][key] * P[q][key]
    f32x4 oacc[2];
    oacc[0] = f32x4{0.f, 0.f, 0.f, 0.f};
    oacc[1] = f32x4{0.f, 0.f, 0.f, 0.f};
#pragma unroll
    for (int kk = 0; kk < 3; ++kk) {
        bf16x8 bp = lds_b8(Pw, frow * 208 + kk * 64 + fk * 16);
#pragma unroll
        for (int mi = 0; mi < 2; ++mi) {
            const int dv = mi * 16 + frow;
            const int cbv = ((wv * 2 + kk * 4 + fk) & 15) ^ (dv & 15);
            bf16x8 av = lds_b8(Vts, dv * 256 + cbv * 16);
            oacc[mi] = __builtin_amdgcn_mfma_f32_16x16x32_bf16(av, bp, oacc[mi], 0, 0, 0);
        }
    }

    // ---- store out (bf16): row i = i0 + wv*16 + frow, col = h*32 + dv
    const int iq = i0 + wv * 16 + frow;
#pragma unroll
    for (int mi = 0; mi < 2; ++mi)
#pragma unroll
        for (int j = 0; j < 4; ++j) {
            const int dv = mi * 16 + g * 4 + j;
            ob[((size_t)(b * S_LEN + iq)) * 256 + h * 32 + dv] = f2bf(oacc[mi][j]);
        }
}

// ---------------------------------------------------------------------------
// out = LayerNorm(a + r); optionally also write bf16 copy.
// ---------------------------------------------------------------------------
template<bool DUAL>
__global__ __launch_bounds__(256, 4)
void add_ln(const float* __restrict__ a, const float* __restrict__ r,
            const float* __restrict__ g, const float* __restrict__ be,
            float* __restrict__ o, u16* __restrict__ ob16)
{
    const int row = blockIdx.x * 4 + (threadIdx.x >> 6);
    const int lane = threadIdx.x & 63;
    const size_t base = (size_t)row * 256 + lane * 4;

    const float4 va = *reinterpret_cast<const float4*>(&a[base]);
    const float4 vr = *reinterpret_cast<const float4*>(&r[base]);
    const float v0 = va.x + vr.x, v1 = va.y + vr.y;
    const float v2 = va.z + vr.z, v3 = va.w + vr.w;

    float sum = v0 + v1 + v2 + v3;
#pragma unroll
    for (int off = 32; off; off >>= 1) sum += __shfl_xor(sum, off);
    const float mean = sum * (1.f / 256.f);

    const float d0 = v0 - mean, d1 = v1 - mean, d2 = v2 - mean, d3 = v3 - mean;
    float ss = d0 * d0 + d1 * d1 + d2 * d2 + d3 * d3;
#pragma unroll
    for (int off = 32; off; off >>= 1) ss += __shfl_xor(ss, off);
    const float rs = rsqrtf(ss * (1.f / 256.f) + 1e-5f);

    const float4 vg = *reinterpret_cast<const float4*>(&g[lane * 4]);
    const float4 vb = *reinterpret_cast<const float4*>(&be[lane * 4]);
    float4 out;
    out.x = d0 * rs * vg.x + vb.x;
    out.y = d1 * rs * vg.y + vb.y;
    out.z = d2 * rs * vg.z + vb.z;
    out.w = d3 * rs * vg.w + vb.w;
    *reinterpret_cast<float4*>(&o[base]) = out;
    if (DUAL) {
        uint2 pk;
        pk.x = (unsigned)f2bf(out.x) | ((unsigned)f2bf(out.y) << 16);
        pk.y = (unsigned)f2bf(out.z) | ((unsigned)f2bf(out.w) << 16);
        *reinterpret_cast<uint2*>(&ob16[base]) = pk;
    }
}

// ---------------------------------------------------------------------------
// fp32 -> bf16 bulk convert (8 elems/thread)
// ---------------------------------------------------------------------------
__global__ void cvt_x_bf16(const float* __restrict__ in, u16* __restrict__ out)
{
    const int i = blockIdx.x * 256 + threadIdx.x;
    const float4* p = reinterpret_cast<const float4*>(in) + (size_t)i * 2;
    const float4 a = p[0], c = p[1];
    uint4 u;
    u.x = (unsigned)f2bf(a.x) | ((unsigned)f2bf(a.y) << 16);
    u.y = (unsigned)f2bf(a.z) | ((unsigned)f2bf(a.w) << 16);
    u.z = (unsigned)f2bf(c.x) | ((unsigned)f2bf(c.y) << 16);
    u.w = (unsigned)f2bf(c.z) | ((unsigned)f2bf(c.w) << 16);
    *(reinterpret_cast<uint4*>(out) + i) = u;
}

// W [256][N] fp32 -> Wt [N][256] bf16
__global__ void cvt_wt(const float* __restrict__ w, u16* __restrict__ wt, int N)
{
    const int n = blockIdx.x, k = threadIdx.x;
    wt[(size_t)n * 256 + k] = f2bf(w[(size_t)k * N + n]);
}

// vb [32768][256] bf16 -> vt [bh][dv 32][S] bf16
__global__ __launch_bounds__(256, 4)
void v_transpose(const u16* __restrict__ vb, u16* __restrict__ vt)
{
    __shared__ u16 L[32][264];
    const int bh = blockIdx.y, b = bh >> 3, h = bh & 7;
    const int s0 = blockIdx.x * 256;
    const int t = threadIdx.x;

    const u16* src = vb + ((size_t)(b * S_LEN + s0 + t)) * 256 + h * 32;
#pragma unroll
    for (int c = 0; c < 4; ++c) {
        uint4 val = *reinterpret_cast<const uint4*>(src + c * 8);
        L[c * 8 + 0][t] = (u16)(val.x & 0xFFFF); L[c * 8 + 1][t] = (u16)(val.x >> 16);
        L[c * 8 + 2][t] = (u16)(val.y & 0xFFFF); L[c * 8 + 3][t] = (u16)(val.y >> 16);
        L[c * 8 + 4][t] = (u16)(val.z & 0xFFFF); L[c * 8 + 5][t] = (u16)(val.z >> 16);
        L[c * 8 + 6][t] = (u16)(val.w & 0xFFFF); L[c * 8 + 7][t] = (u16)(val.w >> 16);
    }
    __syncthreads();
    const int dv = t >> 3, ch = t & 7;
    u16* dst = vt + ((size_t)bh * 32 + dv) * S_LEN + s0 + ch * 32;
#pragma unroll
    for (int c = 0; c < 4; ++c) {
        uint4 u;
        const u16* lp = &L[dv][ch * 32 + c * 8];
        u.x = (unsigned)lp[0] | ((unsigned)lp[1] << 16);
        u.y = (unsigned)lp[2] | ((unsigned)lp[3] << 16);
        u.z = (unsigned)lp[4] | ((unsigned)lp[5] << 16);
        u.w = (unsigned)lp[6] | ((unsigned)lp[7] << 16);
        *reinterpret_cast<uint4*>(dst + c * 8) = u;
    }
}

// ---------------------------------------------------------------------------
extern "C" void kernel_launch(void* const* d_in, const int* in_sizes, int n_in,
                              void* d_out, int out_size, void* d_ws, size_t ws_size,
                              hipStream_t stream)
{
    const float* x   = (const float*)d_in[0];
    const float* Wq  = (const float*)d_in[1];
    const float* bq  = (const float*)d_in[2];
    const float* Wk  = (const float*)d_in[3];
    const float* bk  = (const float*)d_in[4];
    const float* Wv  = (const float*)d_in[5];
    const float* bv  = (const float*)d_in[6];
    const float* Wo  = (const float*)d_in[7];
    const float* bo  = (const float*)d_in[8];
    const float* rel = (const float*)d_in[9];
    const float* g1  = (const float*)d_in[10];
    const float* b1  = (const float*)d_in[11];
    const float* Wl  = (const float*)d_in[12];
    const float* bl  = (const float*)d_in[13];
    const float* g2  = (const float*)d_in[14];
    const float* b2  = (const float*)d_in[15];
    float* out = (float*)d_out;

    u16* qb  = (u16*)d_ws;                       // 32768 x 512 bf16
    u16* kb  = qb  + (size_t)BSROWS * 512;       // 32768 x 512
    u16* vb  = kb  + (size_t)BSROWS * 512;       // 32768 x 256
    u16* vt  = vb  + (size_t)BSROWS * 256;       // [32][32][8192]
    u16* xb  = vt  + (size_t)BSROWS * 256;       // 32768 x 256
    u16* wqt = xb  + (size_t)BSROWS * 256;       // 512 x 256
    u16* wkt = wqt + 512 * 256;
    u16* wvt = wkt + 512 * 256;
    u16* wot = wvt + 256 * 256;
    u16* wlt = wot + 256 * 256;

    float* tmp  = (float*)qb;   // Wo out (qb region: 33.55MB == 32768*256*4)
    float* lin  = (float*)qb;   // Wlin out (after tmp consumed)
    float* xs   = (float*)kb;   // ln1 out fp32
    u16*   xsb  = vb;           // ln1 out bf16 (vb dead after v_transpose)
    u16*   attnb = xb;          // attn out bf16 (xb dead after QKV gemms)

    dim3 blk(256);

    cvt_x_bf16<<<4096, blk, 0, stream>>>(x, xb);
    cvt_wt<<<512, blk, 0, stream>>>(Wq, wqt, 512);
    cvt_wt<<<512, blk, 0, stream>>>(Wk, wkt, 512);
    cvt_wt<<<256, blk, 0, stream>>>(Wv, wvt, 256);
    cvt_wt<<<256, blk, 0, stream>>>(Wo, wot, 256);
    cvt_wt<<<256, blk, 0, stream>>>(Wl, wlt, 256);

    gemm_bf16<false, true><<<dim3(4 * 256), blk, 0, stream>>>(xb, wqt, bq, qb, 512, 4);
    gemm_bf16<false, true><<<dim3(4 * 256), blk, 0, stream>>>(xb, wkt, bk, kb, 512, 4);
    gemm_bf16<false, true><<<dim3(2 * 256), blk, 0, stream>>>(xb, wvt, bv, vb, 256, 2);

    v_transpose<<<dim3(32, 32), blk, 0, stream>>>(vb, vt);

    attn_mfma<<<dim3(S_LEN / 64, NB * NH), blk, 0, stream>>>(qb, kb, vt, rel, attnb);

    gemm_bf16<false, false><<<dim3(2 * 256), blk, 0, stream>>>(attnb, wot, bo, tmp, 256, 2);
    add_ln<true><<<dim3(BSROWS / 4), blk, 0, stream>>>(tmp, x, g1, b1, xs, xsb);
    gemm_bf16<true, false><<<dim3(2 * 256), blk, 0, stream>>>(xsb, wlt, bl, lin, 256, 2);
    add_ln<false><<<dim3(BSROWS / 4), blk, 0, stream>>>(lin, xs, g2, b2, out, nullptr);
}

// Round 10
// 248.652 us; speedup vs baseline: 3.1900x; 1.0402x over previous
//
#include <hip/hip_runtime.h>
#include <math.h>

#define S_LEN 8192
#define NB 4
#define NH 8
#define BSROWS (NB * S_LEN)

typedef __bf16 bf16x8 __attribute__((ext_vector_type(8)));
typedef float f32x4 __attribute__((ext_vector_type(4)));
typedef unsigned short u16;
typedef const __attribute__((address_space(1))) void* as1cv;
typedef __attribute__((address_space(3))) void* as3v;

__device__ __forceinline__ u16 f2bf(float f) {
    union { float f; unsigned int u; } v; v.f = f;
    unsigned int r = v.u + 0x7FFFu + ((v.u >> 16) & 1u);
    return (u16)(r >> 16);
}

__device__ __forceinline__ void gload16(const void* g, void* l) {
    __builtin_amdgcn_global_load_lds((as1cv)g, (as3v)l, 16, 0, 0);
}

__device__ __forceinline__ bf16x8 lds_b8(const u16* base, int byteoff) {
    return *reinterpret_cast<const bf16x8*>(reinterpret_cast<const char*>(base) + byteoff);
}

// ---------------------------------------------------------------------------
// bf16 MFMA GEMM: C[M,N] = A[M,256](bf16) @ W[256,N] + bias.
// Wt is pre-transposed [N][256] bf16. BM=BN=128, BK=64, 4 waves (2x2 of 64x64).
// LDS rows 128B, XOR-swizzled chunk ^ (row&7); staged via global_load_lds w=16.
// ---------------------------------------------------------------------------
template<bool RELU, bool BF16OUT>
__global__ __launch_bounds__(256, 2)
void gemm_bf16(const u16* __restrict__ A, const u16* __restrict__ Wt,
               const float* __restrict__ bias, void* __restrict__ Cv,
               int N, int nbx)
{
    __shared__ u16 As[128 * 64];
    __shared__ u16 Bs[128 * 64];

    const int t = threadIdx.x;
    const int wv = t >> 6, ln = t & 63;

    // XCD-aware swizzle (gridDim.x % 8 == 0 for all our launches)
    const int nwg = gridDim.x;
    const int qq = nwg >> 3;
    const int swz = (blockIdx.x & 7) * qq + (blockIdx.x >> 3);
    const int by = swz / nbx, bx = swz % nbx;
    const int rbase = by * 128, cbase = bx * 128;

    const int wr = wv >> 1, wc = wv & 1;
    const int frow = ln & 15, fk = ln >> 4;

    f32x4 acc[4][4];
#pragma unroll
    for (int i = 0; i < 4; ++i)
#pragma unroll
        for (int j = 0; j < 4; ++j) acc[i][j] = f32x4{0.f, 0.f, 0.f, 0.f};

    const int srow_b = (ln >> 3);        // 0..7 within wave segment
    const int scb    = ln & 7;

    for (int k0 = 0; k0 < 256; k0 += 64) {
#pragma unroll
        for (int r = 0; r < 4; ++r) {
            const int rowA = r * 32 + wv * 8 + srow_b;
            const int cbs = scb ^ (rowA & 7);
            gload16(A + (size_t)(rbase + rowA) * 256 + k0 + cbs * 8,
                    As + r * 2048 + wv * 512);
            gload16(Wt + (size_t)(cbase + rowA) * 256 + k0 + cbs * 8,
                    Bs + r * 2048 + wv * 512);
        }
        __syncthreads();

        bf16x8 af[4][2], bfr[4][2];
#pragma unroll
        for (int mi = 0; mi < 4; ++mi)
#pragma unroll
            for (int kk = 0; kk < 2; ++kk) {
                const int row = wr * 64 + mi * 16 + frow;
                const int cb = (kk * 4 + fk) ^ (row & 7);
                af[mi][kk] = lds_b8(As, row * 128 + cb * 16);
            }
#pragma unroll
        for (int ni = 0; ni < 4; ++ni)
#pragma unroll
            for (int kk = 0; kk < 2; ++kk) {
                const int row = wc * 64 + ni * 16 + frow;
                const int cb = (kk * 4 + fk) ^ (row & 7);
                bfr[ni][kk] = lds_b8(Bs, row * 128 + cb * 16);
            }
#pragma unroll
        for (int mi = 0; mi < 4; ++mi)
#pragma unroll
            for (int ni = 0; ni < 4; ++ni)
#pragma unroll
                for (int kk = 0; kk < 2; ++kk)
                    acc[mi][ni] = __builtin_amdgcn_mfma_f32_16x16x32_bf16(
                        af[mi][kk], bfr[ni][kk], acc[mi][ni], 0, 0, 0);
        __syncthreads();
    }

    float cbias[4];
#pragma unroll
    for (int ni = 0; ni < 4; ++ni)
        cbias[ni] = bias[cbase + wc * 64 + ni * 16 + frow];

#pragma unroll
    for (int mi = 0; mi < 4; ++mi) {
        const int row0 = rbase + wr * 64 + mi * 16 + fk * 4;
#pragma unroll
        for (int ni = 0; ni < 4; ++ni) {
            const int col = cbase + wc * 64 + ni * 16 + frow;
#pragma unroll
            for (int j = 0; j < 4; ++j) {
                float v = acc[mi][ni][j] + cbias[ni];
                if (RELU) v = fmaxf(v, 0.f);
                if (BF16OUT)
                    ((u16*)Cv)[(size_t)(row0 + j) * N + col] = f2bf(v);
                else
                    ((float*)Cv)[(size_t)(row0 + j) * N + col] = v;
            }
        }
    }
}

// ---------------------------------------------------------------------------
// MFMA banded attention over the fused QKV buffer [BSROWS][1280] bf16:
// q cols [0,512), k cols [512,1024), v handled via pre-transposed vt.
// Grid (S/64, B*H), 256 thr = 4 waves, wave = 16 queries.
// Keys tile rows 0..127 = positions i0-32 .. i0+95. Wave wv uses key subtiles
// ni=0..4 (80 keys from wv*16). Softmax in C-layout; P->LDS bf16; PV via
// out^T = V^T @ P^T. Out-of-range staging positions CLAMPED (masked in
// softmax; clamped data finite so 0*x can't NaN).
// ---------------------------------------------------------------------------
__global__ __launch_bounds__(256, 3)
void attn_mfma(const u16* __restrict__ qkv, const u16* __restrict__ vt,
               const float* __restrict__ rel, u16* __restrict__ ob)
{
    __shared__ u16 Ks[128 * 64];    // [key][d]  swz ^(key&7)
    __shared__ u16 Qs[64 * 64];     // [q][d]    swz ^(q&7)
    __shared__ u16 Vts[32 * 128];   // [dv][key] swz ^(dv&15)
    __shared__ u16 Ps[4][16 * 104]; // per-wave P[q][key_local], stride 104
    __shared__ float rbs[72];

    const int t = threadIdx.x, wv = t >> 6, ln = t & 63;
    const int bh = blockIdx.y, b = bh >> 3, h = bh & 7;
    const int i0 = blockIdx.x * 64;

    // stage K: 128 rows x 128B (row stride 2560B, +1024B col offset; clamped)
#pragma unroll
    for (int r = 0; r < 4; ++r) {
        const int row = r * 32 + wv * 8 + (ln >> 3);
        const int cbs = (ln & 7) ^ (row & 7);
        int pos = i0 - 32 + row;
        pos = pos < 0 ? 0 : (pos >= S_LEN ? S_LEN - 1 : pos);
        const long long grow = (long long)b * S_LEN + pos;
        gload16((const char*)qkv + grow * 2560 + 1024 + h * 128 + cbs * 16,
                Ks + r * 2048 + wv * 512);
    }
    // stage Q: 64 rows x 128B (always in range)
#pragma unroll
    for (int r = 0; r < 2; ++r) {
        const int row = r * 32 + wv * 8 + (ln >> 3);
        const int cbs = (ln & 7) ^ (row & 7);
        gload16((const char*)qkv + ((size_t)(b * S_LEN + i0 + row)) * 2560 + h * 128 + cbs * 16,
                Qs + r * 2048 + wv * 512);
    }
    // stage V^T: 32 rows x 256B (byte offset clamped into the dv-row)
#pragma unroll
    for (int r = 0; r < 2; ++r) {
        const int row = r * 16 + wv * 4 + (ln >> 4);
        const int cbs = (ln & 15) ^ (row & 15);
        long long off = (long long)(i0 - 32) * 2 + cbs * 16;
        off = off < 0 ? 0 : (off > (long long)(S_LEN * 2 - 16) ? (long long)(S_LEN * 2 - 16) : off);
        gload16((const char*)vt + ((size_t)bh * 32 + row) * (S_LEN * 2) + off,
                Vts + r * 2048 + wv * 512);
    }
    if (t < 65) rbs[t] = rel[h * 65 + t];
    __syncthreads();

    const int frow = ln & 15, fk = ln >> 4, g = fk;

    // ---- scores: S = Q @ K^T
    bf16x8 aq[2];
    const int qrow = wv * 16 + frow;
#pragma unroll
    for (int kk = 0; kk < 2; ++kk) {
        const int cb = (kk * 4 + fk) ^ (qrow & 7);
        aq[kk] = lds_b8(Qs, qrow * 128 + cb * 16);
    }
    f32x4 sacc[5];
#pragma unroll
    for (int ni = 0; ni < 5; ++ni) {
        sacc[ni] = f32x4{0.f, 0.f, 0.f, 0.f};
        const int krow = wv * 16 + ni * 16 + frow;
#pragma unroll
        for (int kk = 0; kk < 2; ++kk) {
            const int cb = (kk * 4 + fk) ^ (krow & 7);
            bf16x8 bk = lds_b8(Ks, krow * 128 + cb * 16);
            sacc[ni] = __builtin_amdgcn_mfma_f32_16x16x32_bf16(aq[kk], bk, sacc[ni], 0, 0, 0);
        }
    }

    // ---- softmax (rows q = wv*16 + g*4 + j; cols key = wv*16 + ni*16 + frow)
    float p[5][4];
#pragma unroll
    for (int j = 0; j < 4; ++j) {
        const int qloc = g * 4 + j;                 // within wave tile
        const int iq = i0 + wv * 16 + qloc;         // global query
        float mx = -1e30f;
#pragma unroll
        for (int ni = 0; ni < 5; ++ni) {
            const int w = ni * 16 + frow - qloc;    // window offset
            const long long pos = (long long)iq - 32 + w;
            const bool valid = (w >= 0) & (w <= 64) & (pos >= 0) & (pos < S_LEN);
            const int wc2 = w < 0 ? 0 : (w > 64 ? 64 : w);
            const float s = valid ? fmaf(sacc[ni][j], 0.125f, rbs[wc2]) : -1e9f;
            p[ni][j] = s;
            mx = fmaxf(mx, s);
        }
        mx = fmaxf(mx, __shfl_xor(mx, 1));
        mx = fmaxf(mx, __shfl_xor(mx, 2));
        mx = fmaxf(mx, __shfl_xor(mx, 4));
        mx = fmaxf(mx, __shfl_xor(mx, 8));
        float sum = 0.f;
#pragma unroll
        for (int ni = 0; ni < 5; ++ni) {
            const float e = __expf(p[ni][j] - mx);
            p[ni][j] = e; sum += e;
        }
        sum += __shfl_xor(sum, 1);
        sum += __shfl_xor(sum, 2);
        sum += __shfl_xor(sum, 4);
        sum += __shfl_xor(sum, 8);
        const float inv = 1.f / sum;
#pragma unroll
        for (int ni = 0; ni < 5; ++ni) p[ni][j] *= inv;
    }

    // ---- P -> LDS (bf16), zero-pad key_local 80..95
    u16* Pw = &Ps[wv][0];
    {
        const int zr = ln >> 2, zc = 80 + (ln & 3) * 4;
        *reinterpret_cast<uint2*>(Pw + zr * 104 + zc) = uint2{0u, 0u};
    }
#pragma unroll
    for (int ni = 0; ni < 5; ++ni)
#pragma unroll
        for (int j = 0; j < 4; ++j)
            Pw[(g * 4 + j) * 104 + ni * 16 + frow] = f2bf(p[ni][j]);

    // barrier: P is written by one lane and read by another (cross-lane LDS
    // dep the compiler can't see). Cheap and guarantees lgkmcnt ordering.
    __syncthreads();

    // ---- PV: out^T[dv][q] = sum_key V^T[dv][key] * P[q][key]
    f32x4 oacc[2];
    oacc[0] = f32x4{0.f, 0.f, 0.f, 0.f};
    oacc[1] = f32x4{0.f, 0.f, 0.f, 0.f};
#pragma unroll
    for (int kk = 0; kk < 3; ++kk) {
        bf16x8 bp = lds_b8(Pw, frow * 208 + kk * 64 + fk * 16);
#pragma unroll
        for (int mi = 0; mi < 2; ++mi) {
            const int dv = mi * 16 + frow;
            const int cbv = ((wv * 2 + kk * 4 + fk) & 15) ^ (dv & 15);
            bf16x8 av = lds_b8(Vts, dv * 256 + cbv * 16);
            oacc[mi] = __builtin_amdgcn_mfma_f32_16x16x32_bf16(av, bp, oacc[mi], 0, 0, 0);
        }
    }

    // ---- store out (bf16): row i = i0 + wv*16 + frow, col = h*32 + dv
    const int iq = i0 + wv * 16 + frow;
#pragma unroll
    for (int mi = 0; mi < 2; ++mi)
#pragma unroll
        for (int j = 0; j < 4; ++j) {
            const int dv = mi * 16 + g * 4 + j;
            ob[((size_t)(b * S_LEN + iq)) * 256 + h * 32 + dv] = f2bf(oacc[mi][j]);
        }
}

// ---------------------------------------------------------------------------
// out = LayerNorm(a + r); optionally also write bf16 copy.
// ---------------------------------------------------------------------------
template<bool DUAL>
__global__ __launch_bounds__(256, 4)
void add_ln(const float* __restrict__ a, const float* __restrict__ r,
            const float* __restrict__ g, const float* __restrict__ be,
            float* __restrict__ o, u16* __restrict__ ob16)
{
    const int row = blockIdx.x * 4 + (threadIdx.x >> 6);
    const int lane = threadIdx.x & 63;
    const size_t base = (size_t)row * 256 + lane * 4;

    const float4 va = *reinterpret_cast<const float4*>(&a[base]);
    const float4 vr = *reinterpret_cast<const float4*>(&r[base]);
    const float v0 = va.x + vr.x, v1 = va.y + vr.y;
    const float v2 = va.z + vr.z, v3 = va.w + vr.w;

    float sum = v0 + v1 + v2 + v3;
#pragma unroll
    for (int off = 32; off; off >>= 1) sum += __shfl_xor(sum, off);
    const float mean = sum * (1.f / 256.f);

    const float d0 = v0 - mean, d1 = v1 - mean, d2 = v2 - mean, d3 = v3 - mean;
    float ss = d0 * d0 + d1 * d1 + d2 * d2 + d3 * d3;
#pragma unroll
    for (int off = 32; off; off >>= 1) ss += __shfl_xor(ss, off);
    const float rs = rsqrtf(ss * (1.f / 256.f) + 1e-5f);

    const float4 vg = *reinterpret_cast<const float4*>(&g[lane * 4]);
    const float4 vb = *reinterpret_cast<const float4*>(&be[lane * 4]);
    float4 out;
    out.x = d0 * rs * vg.x + vb.x;
    out.y = d1 * rs * vg.y + vb.y;
    out.z = d2 * rs * vg.z + vb.z;
    out.w = d3 * rs * vg.w + vb.w;
    *reinterpret_cast<float4*>(&o[base]) = out;
    if (DUAL) {
        uint2 pk;
        pk.x = (unsigned)f2bf(out.x) | ((unsigned)f2bf(out.y) << 16);
        pk.y = (unsigned)f2bf(out.z) | ((unsigned)f2bf(out.w) << 16);
        *reinterpret_cast<uint2*>(&ob16[base]) = pk;
    }
}

// ---------------------------------------------------------------------------
// fp32 -> bf16 bulk convert (8 elems/thread)
// ---------------------------------------------------------------------------
__global__ void cvt_x_bf16(const float* __restrict__ in, u16* __restrict__ out)
{
    const int i = blockIdx.x * 256 + threadIdx.x;
    const float4* p = reinterpret_cast<const float4*>(in) + (size_t)i * 2;
    const float4 a = p[0], c = p[1];
    uint4 u;
    u.x = (unsigned)f2bf(a.x) | ((unsigned)f2bf(a.y) << 16);
    u.y = (unsigned)f2bf(a.z) | ((unsigned)f2bf(a.w) << 16);
    u.z = (unsigned)f2bf(c.x) | ((unsigned)f2bf(c.y) << 16);
    u.w = (unsigned)f2bf(c.z) | ((unsigned)f2bf(c.w) << 16);
    *(reinterpret_cast<uint4*>(out) + i) = u;
}

// W [256][N] fp32 -> Wt rows [roff, roff+N) of [*][256] bf16 (transposed)
__global__ void cvt_wt(const float* __restrict__ w, u16* __restrict__ wt,
                       int N, int roff)
{
    const int n = blockIdx.x, k = threadIdx.x;
    wt[(size_t)(n + roff) * 256 + k] = f2bf(w[(size_t)k * N + n]);
}

// concat bq|bk|bv -> [1280] fp32
__global__ void bias_cat(const float* __restrict__ bq, const float* __restrict__ bk,
                         const float* __restrict__ bv, float* __restrict__ o)
{
    const int i = blockIdx.x * 256 + threadIdx.x;
    o[i] = i < 512 ? bq[i] : (i < 1024 ? bk[i - 512] : bv[i - 1024]);
}

// qkv [32768][1280] bf16 (v at cols 1024+) -> vt [bh][dv 32][S] bf16
__global__ __launch_bounds__(256, 4)
void v_transpose(const u16* __restrict__ qkv, u16* __restrict__ vt)
{
    __shared__ u16 L[32][264];
    const int bh = blockIdx.y, b = bh >> 3, h = bh & 7;
    const int s0 = blockIdx.x * 256;
    const int t = threadIdx.x;

    const u16* src = qkv + ((size_t)(b * S_LEN + s0 + t)) * 1280 + 1024 + h * 32;
#pragma unroll
    for (int c = 0; c < 4; ++c) {
        uint4 val = *reinterpret_cast<const uint4*>(src + c * 8);
        L[c * 8 + 0][t] = (u16)(val.x & 0xFFFF); L[c * 8 + 1][t] = (u16)(val.x >> 16);
        L[c * 8 + 2][t] = (u16)(val.y & 0xFFFF); L[c * 8 + 3][t] = (u16)(val.y >> 16);
        L[c * 8 + 4][t] = (u16)(val.z & 0xFFFF); L[c * 8 + 5][t] = (u16)(val.z >> 16);
        L[c * 8 + 6][t] = (u16)(val.w & 0xFFFF); L[c * 8 + 7][t] = (u16)(val.w >> 16);
    }
    __syncthreads();
    const int dv = t >> 3, ch = t & 7;
    u16* dst = vt + ((size_t)bh * 32 + dv) * S_LEN + s0 + ch * 32;
#pragma unroll
    for (int c = 0; c < 4; ++c) {
        uint4 u;
        const u16* lp = &L[dv][ch * 32 + c * 8];
        u.x = (unsigned)lp[0] | ((unsigned)lp[1] << 16);
        u.y = (unsigned)lp[2] | ((unsigned)lp[3] << 16);
        u.z = (unsigned)lp[4] | ((unsigned)lp[5] << 16);
        u.w = (unsigned)lp[6] | ((unsigned)lp[7] << 16);
        *reinterpret_cast<uint4*>(dst + c * 8) = u;
    }
}

// ---------------------------------------------------------------------------
extern "C" void kernel_launch(void* const* d_in, const int* in_sizes, int n_in,
                              void* d_out, int out_size, void* d_ws, size_t ws_size,
                              hipStream_t stream)
{
    const float* x   = (const float*)d_in[0];
    const float* Wq  = (const float*)d_in[1];
    const float* bq  = (const float*)d_in[2];
    const float* Wk  = (const float*)d_in[3];
    const float* bk  = (const float*)d_in[4];
    const float* Wv  = (const float*)d_in[5];
    const float* bv  = (const float*)d_in[6];
    const float* Wo  = (const float*)d_in[7];
    const float* bo  = (const float*)d_in[8];
    const float* rel = (const float*)d_in[9];
    const float* g1  = (const float*)d_in[10];
    const float* b1  = (const float*)d_in[11];
    const float* Wl  = (const float*)d_in[12];
    const float* bl  = (const float*)d_in[13];
    const float* g2  = (const float*)d_in[14];
    const float* b2  = (const float*)d_in[15];
    float* out = (float*)d_out;

    // workspace layout (u16 elements)
    u16* qkvb  = (u16*)d_ws;                        // [32768][1280] bf16, 83.9MB
    u16* vt    = qkvb  + (size_t)BSROWS * 1280;     // [32][32][8192], 16.8MB
    u16* xb    = vt    + (size_t)BSROWS * 256;      // [32768][256] bf16, 16.8MB
    u16* wqkvt = xb    + (size_t)BSROWS * 256;      // [1280][256] bf16
    u16* wot   = wqkvt + 1280 * 256;                // [256][256]
    u16* wlt   = wot   + 256 * 256;                 // [256][256]
    float* bqkv = (float*)(wlt + 256 * 256);        // [1280] fp32

    // fp32 reuse of qkvb region (41.9M u16 slots = 20.9M floats):
    float* tmp = (float*)qkvb;                      // Wo out,  floats [0, 8.4M)
    float* xs  = (float*)qkvb + (size_t)BSROWS * 256; // ln1 out, floats [8.4M, 16.8M)
    float* lin = tmp;                               // Wlin out (tmp dead by then)
    u16*   xsb   = vt;   // ln1 bf16 (vt dead after attn)
    u16*   attnb = xb;   // attn out bf16 (xb dead after QKV gemm)

    dim3 blk(256);

    cvt_x_bf16<<<4096, blk, 0, stream>>>(x, xb);
    cvt_wt<<<512, blk, 0, stream>>>(Wq, wqkvt, 512, 0);
    cvt_wt<<<512, blk, 0, stream>>>(Wk, wqkvt, 512, 512);
    cvt_wt<<<256, blk, 0, stream>>>(Wv, wqkvt, 256, 1024);
    cvt_wt<<<256, blk, 0, stream>>>(Wo, wot, 256, 0);
    cvt_wt<<<256, blk, 0, stream>>>(Wl, wlt, 256, 0);
    bias_cat<<<5, blk, 0, stream>>>(bq, bk, bv, bqkv);

    // fused QKV GEMM: [32768][256] @ [256][1280] -> qkvb
    gemm_bf16<false, true><<<dim3(10 * 256), blk, 0, stream>>>(xb, wqkvt, bqkv, qkvb, 1280, 10);

    v_transpose<<<dim3(32, 32), blk, 0, stream>>>(qkvb, vt);

    attn_mfma<<<dim3(S_LEN / 64, NB * NH), blk, 0, stream>>>(qkvb, vt, rel, attnb);

    gemm_bf16<false, false><<<dim3(2 * 256), blk, 0, stream>>>(attnb, wot, bo, tmp, 256, 2);
    add_ln<true><<<dim3(BSROWS / 4), blk, 0, stream>>>(tmp, x, g1, b1, xs, xsb);
    gemm_bf16<true, false><<<dim3(2 * 256), blk, 0, stream>>>(xsb, wlt, bl, lin, 256, 2);
    add_ln<false><<<dim3(BSROWS / 4), blk, 0, stream>>>(lin, xs, g2, b2, out, nullptr);
}

// Round 11
// 234.427 us; speedup vs baseline: 3.3836x; 1.0607x over previous
//
#include <hip/hip_runtime.h>
#include <math.h>

#define S_LEN 8192
#define NB 4
#define NH 8
#define BSROWS (NB * S_LEN)

typedef __bf16 bf16x8 __attribute__((ext_vector_type(8)));
typedef float f32x4 __attribute__((ext_vector_type(4)));
typedef unsigned short u16;
typedef const __attribute__((address_space(1))) void* as1cv;
typedef __attribute__((address_space(3))) void* as3v;

__device__ __forceinline__ u16 f2bf(float f) {
    union { float f; unsigned int u; } v; v.f = f;
    unsigned int r = v.u + 0x7FFFu + ((v.u >> 16) & 1u);
    return (u16)(r >> 16);
}

__device__ __forceinline__ void gload16(const void* g, void* l) {
    __builtin_amdgcn_global_load_lds((as1cv)g, (as3v)l, 16, 0, 0);
}

__device__ __forceinline__ bf16x8 lds_b8(const u16* base, int byteoff) {
    return *reinterpret_cast<const bf16x8*>(reinterpret_cast<const char*>(base) + byteoff);
}

// ---------------------------------------------------------------------------
// bf16 MFMA GEMM: C[M,N] = A[M,256](bf16) @ W[256,N] + bias.
// Wt pre-transposed [N][256] bf16. BM=BN=128, BK=64, 4 waves (2x2 of 64x64).
// LDS rows 128B, XOR-swizzled chunk ^ (row&7); staged via global_load_lds w=16.
// VFUSE: blocks with cbase>=1024 (the V columns of the fused QKV output)
// write DIRECTLY into vt [bh][dv 32][S] transposed layout instead of Cv.
// ---------------------------------------------------------------------------
template<bool RELU, bool BF16OUT, bool VFUSE>
__global__ __launch_bounds__(256, 2)
void gemm_bf16(const u16* __restrict__ A, const u16* __restrict__ Wt,
               const float* __restrict__ bias, void* __restrict__ Cv,
               u16* __restrict__ vtout, int N, int nbx)
{
    __shared__ u16 As[128 * 64];
    __shared__ u16 Bs[128 * 64];

    const int t = threadIdx.x;
    const int wv = t >> 6, ln = t & 63;

    // XCD-aware swizzle (gridDim.x % 8 == 0 for all our launches)
    const int nwg = gridDim.x;
    const int qq = nwg >> 3;
    const int swz = (blockIdx.x & 7) * qq + (blockIdx.x >> 3);
    const int by = swz / nbx, bx = swz % nbx;
    const int rbase = by * 128, cbase = bx * 128;

    const int wr = wv >> 1, wc = wv & 1;
    const int frow = ln & 15, fk = ln >> 4;

    f32x4 acc[4][4];
#pragma unroll
    for (int i = 0; i < 4; ++i)
#pragma unroll
        for (int j = 0; j < 4; ++j) acc[i][j] = f32x4{0.f, 0.f, 0.f, 0.f};

    const int srow_b = (ln >> 3);        // 0..7 within wave segment
    const int scb    = ln & 7;

    for (int k0 = 0; k0 < 256; k0 += 64) {
#pragma unroll
        for (int r = 0; r < 4; ++r) {
            const int rowA = r * 32 + wv * 8 + srow_b;
            const int cbs = scb ^ (rowA & 7);
            gload16(A + (size_t)(rbase + rowA) * 256 + k0 + cbs * 8,
                    As + r * 2048 + wv * 512);
            gload16(Wt + (size_t)(cbase + rowA) * 256 + k0 + cbs * 8,
                    Bs + r * 2048 + wv * 512);
        }
        __syncthreads();

        bf16x8 af[4][2], bfr[4][2];
#pragma unroll
        for (int mi = 0; mi < 4; ++mi)
#pragma unroll
            for (int kk = 0; kk < 2; ++kk) {
                const int row = wr * 64 + mi * 16 + frow;
                const int cb = (kk * 4 + fk) ^ (row & 7);
                af[mi][kk] = lds_b8(As, row * 128 + cb * 16);
            }
#pragma unroll
        for (int ni = 0; ni < 4; ++ni)
#pragma unroll
            for (int kk = 0; kk < 2; ++kk) {
                const int row = wc * 64 + ni * 16 + frow;
                const int cb = (kk * 4 + fk) ^ (row & 7);
                bfr[ni][kk] = lds_b8(Bs, row * 128 + cb * 16);
            }
#pragma unroll
        for (int mi = 0; mi < 4; ++mi)
#pragma unroll
            for (int ni = 0; ni < 4; ++ni)
#pragma unroll
                for (int kk = 0; kk < 2; ++kk)
                    acc[mi][ni] = __builtin_amdgcn_mfma_f32_16x16x32_bf16(
                        af[mi][kk], bfr[ni][kk], acc[mi][ni], 0, 0, 0);
        __syncthreads();
    }

    float cbias[4];
#pragma unroll
    for (int ni = 0; ni < 4; ++ni)
        cbias[ni] = bias[cbase + wc * 64 + ni * 16 + frow];

    if (VFUSE && cbase >= 1024) {
        // V columns -> vt[((b*8+h)*32+dv)][s], 4 consecutive s packed per store
#pragma unroll
        for (int mi = 0; mi < 4; ++mi) {
            const int row0 = rbase + wr * 64 + mi * 16 + fk * 4;
            const int b = row0 >> 13, s = row0 & 8191;
#pragma unroll
            for (int ni = 0; ni < 4; ++ni) {
                const int vcol = cbase - 1024 + wc * 64 + ni * 16 + frow;
                const int h = vcol >> 5, dv = vcol & 31;
                uint2 pk;
                pk.x = (unsigned)f2bf(acc[mi][ni][0] + cbias[ni]) |
                       ((unsigned)f2bf(acc[mi][ni][1] + cbias[ni]) << 16);
                pk.y = (unsigned)f2bf(acc[mi][ni][2] + cbias[ni]) |
                       ((unsigned)f2bf(acc[mi][ni][3] + cbias[ni]) << 16);
                *reinterpret_cast<uint2*>(
                    vtout + ((size_t)((b * 8 + h) * 32 + dv)) * S_LEN + s) = pk;
            }
        }
        return;
    }

#pragma unroll
    for (int mi = 0; mi < 4; ++mi) {
        const int row0 = rbase + wr * 64 + mi * 16 + fk * 4;
#pragma unroll
        for (int ni = 0; ni < 4; ++ni) {
            const int col = cbase + wc * 64 + ni * 16 + frow;
#pragma unroll
            for (int j = 0; j < 4; ++j) {
                float v = acc[mi][ni][j] + cbias[ni];
                if (RELU) v = fmaxf(v, 0.f);
                if (BF16OUT)
                    ((u16*)Cv)[(size_t)(row0 + j) * N + col] = f2bf(v);
                else
                    ((float*)Cv)[(size_t)(row0 + j) * N + col] = v;
            }
        }
    }
}

// ---------------------------------------------------------------------------
// MFMA banded attention over the fused QKV buffer [BSROWS][1280] bf16:
// q cols [0,512), k cols [512,1024); V comes from vt (written by GEMM VFUSE).
// Grid (S/64, B*H), 256 thr = 4 waves, wave = 16 queries.
// Out-of-range staging positions CLAMPED (masked in softmax; finite data).
// ---------------------------------------------------------------------------
__global__ __launch_bounds__(256, 3)
void attn_mfma(const u16* __restrict__ qkv, const u16* __restrict__ vt,
               const float* __restrict__ rel, u16* __restrict__ ob)
{
    __shared__ u16 Ks[128 * 64];    // [key][d]  swz ^(key&7)
    __shared__ u16 Qs[64 * 64];     // [q][d]    swz ^(q&7)
    __shared__ u16 Vts[32 * 128];   // [dv][key] swz ^(dv&15)
    __shared__ u16 Ps[4][16 * 104]; // per-wave P[q][key_local], stride 104
    __shared__ float rbs[72];

    const int t = threadIdx.x, wv = t >> 6, ln = t & 63;
    const int bh = blockIdx.y, b = bh >> 3, h = bh & 7;
    const int i0 = blockIdx.x * 64;

    // stage K: 128 rows x 128B (row stride 2560B, +1024B col offset; clamped)
#pragma unroll
    for (int r = 0; r < 4; ++r) {
        const int row = r * 32 + wv * 8 + (ln >> 3);
        const int cbs = (ln & 7) ^ (row & 7);
        int pos = i0 - 32 + row;
        pos = pos < 0 ? 0 : (pos >= S_LEN ? S_LEN - 1 : pos);
        const long long grow = (long long)b * S_LEN + pos;
        gload16((const char*)qkv + grow * 2560 + 1024 + h * 128 + cbs * 16,
                Ks + r * 2048 + wv * 512);
    }
    // stage Q: 64 rows x 128B (always in range)
#pragma unroll
    for (int r = 0; r < 2; ++r) {
        const int row = r * 32 + wv * 8 + (ln >> 3);
        const int cbs = (ln & 7) ^ (row & 7);
        gload16((const char*)qkv + ((size_t)(b * S_LEN + i0 + row)) * 2560 + h * 128 + cbs * 16,
                Qs + r * 2048 + wv * 512);
    }
    // stage V^T: 32 rows x 256B (byte offset clamped into the dv-row)
#pragma unroll
    for (int r = 0; r < 2; ++r) {
        const int row = r * 16 + wv * 4 + (ln >> 4);
        const int cbs = (ln & 15) ^ (row & 15);
        long long off = (long long)(i0 - 32) * 2 + cbs * 16;
        off = off < 0 ? 0 : (off > (long long)(S_LEN * 2 - 16) ? (long long)(S_LEN * 2 - 16) : off);
        gload16((const char*)vt + ((size_t)bh * 32 + row) * (S_LEN * 2) + off,
                Vts + r * 2048 + wv * 512);
    }
    if (t < 65) rbs[t] = rel[h * 65 + t];
    __syncthreads();

    const int frow = ln & 15, fk = ln >> 4, g = fk;

    // ---- scores: S = Q @ K^T
    bf16x8 aq[2];
    const int qrow = wv * 16 + frow;
#pragma unroll
    for (int kk = 0; kk < 2; ++kk) {
        const int cb = (kk * 4 + fk) ^ (qrow & 7);
        aq[kk] = lds_b8(Qs, qrow * 128 + cb * 16);
    }
    f32x4 sacc[5];
#pragma unroll
    for (int ni = 0; ni < 5; ++ni) {
        sacc[ni] = f32x4{0.f, 0.f, 0.f, 0.f};
        const int krow = wv * 16 + ni * 16 + frow;
#pragma unroll
        for (int kk = 0; kk < 2; ++kk) {
            const int cb = (kk * 4 + fk) ^ (krow & 7);
            bf16x8 bk = lds_b8(Ks, krow * 128 + cb * 16);
            sacc[ni] = __builtin_amdgcn_mfma_f32_16x16x32_bf16(aq[kk], bk, sacc[ni], 0, 0, 0);
        }
    }

    // ---- softmax (rows q = wv*16 + g*4 + j; cols key = wv*16 + ni*16 + frow)
    float p[5][4];
#pragma unroll
    for (int j = 0; j < 4; ++j) {
        const int qloc = g * 4 + j;                 // within wave tile
        const int iq = i0 + wv * 16 + qloc;         // global query
        float mx = -1e30f;
#pragma unroll
        for (int ni = 0; ni < 5; ++ni) {
            const int w = ni * 16 + frow - qloc;    // window offset
            const long long pos = (long long)iq - 32 + w;
            const bool valid = (w >= 0) & (w <= 64) & (pos >= 0) & (pos < S_LEN);
            const int wc2 = w < 0 ? 0 : (w > 64 ? 64 : w);
            const float s = valid ? fmaf(sacc[ni][j], 0.125f, rbs[wc2]) : -1e9f;
            p[ni][j] = s;
            mx = fmaxf(mx, s);
        }
        mx = fmaxf(mx, __shfl_xor(mx, 1));
        mx = fmaxf(mx, __shfl_xor(mx, 2));
        mx = fmaxf(mx, __shfl_xor(mx, 4));
        mx = fmaxf(mx, __shfl_xor(mx, 8));
        float sum = 0.f;
#pragma unroll
        for (int ni = 0; ni < 5; ++ni) {
            const float e = __expf(p[ni][j] - mx);
            p[ni][j] = e; sum += e;
        }
        sum += __shfl_xor(sum, 1);
        sum += __shfl_xor(sum, 2);
        sum += __shfl_xor(sum, 4);
        sum += __shfl_xor(sum, 8);
        const float inv = 1.f / sum;
#pragma unroll
        for (int ni = 0; ni < 5; ++ni) p[ni][j] *= inv;
    }

    // ---- P -> LDS (bf16), zero-pad key_local 80..95
    u16* Pw = &Ps[wv][0];
    {
        const int zr = ln >> 2, zc = 80 + (ln & 3) * 4;
        *reinterpret_cast<uint2*>(Pw + zr * 104 + zc) = uint2{0u, 0u};
    }
#pragma unroll
    for (int ni = 0; ni < 5; ++ni)
#pragma unroll
        for (int j = 0; j < 4; ++j)
            Pw[(g * 4 + j) * 104 + ni * 16 + frow] = f2bf(p[ni][j]);

    // barrier: P is written by one lane and read by another (cross-lane LDS
    // dep the compiler can't see). Cheap and guarantees lgkmcnt ordering.
    __syncthreads();

    // ---- PV: out^T[dv][q] = sum_key V^T[dv][key] * P[q][key]
    f32x4 oacc[2];
    oacc[0] = f32x4{0.f, 0.f, 0.f, 0.f};
    oacc[1] = f32x4{0.f, 0.f, 0.f, 0.f};
#pragma unroll
    for (int kk = 0; kk < 3; ++kk) {
        bf16x8 bp = lds_b8(Pw, frow * 208 + kk * 64 + fk * 16);
#pragma unroll
        for (int mi = 0; mi < 2; ++mi) {
            const int dv = mi * 16 + frow;
            const int cbv = ((wv * 2 + kk * 4 + fk) & 15) ^ (dv & 15);
            bf16x8 av = lds_b8(Vts, dv * 256 + cbv * 16);
            oacc[mi] = __builtin_amdgcn_mfma_f32_16x16x32_bf16(av, bp, oacc[mi], 0, 0, 0);
        }
    }

    // ---- store out (bf16): row i = i0 + wv*16 + frow, col = h*32 + dv
    const int iq = i0 + wv * 16 + frow;
#pragma unroll
    for (int mi = 0; mi < 2; ++mi)
#pragma unroll
        for (int j = 0; j < 4; ++j) {
            const int dv = mi * 16 + g * 4 + j;
            ob[((size_t)(b * S_LEN + iq)) * 256 + h * 32 + dv] = f2bf(oacc[mi][j]);
        }
}

// ---------------------------------------------------------------------------
// out = LayerNorm(a + r); optionally also write bf16 copy.
// ---------------------------------------------------------------------------
template<bool DUAL>
__global__ __launch_bounds__(256, 4)
void add_ln(const float* __restrict__ a, const float* __restrict__ r,
            const float* __restrict__ g, const float* __restrict__ be,
            float* __restrict__ o, u16* __restrict__ ob16)
{
    const int row = blockIdx.x * 4 + (threadIdx.x >> 6);
    const int lane = threadIdx.x & 63;
    const size_t base = (size_t)row * 256 + lane * 4;

    const float4 va = *reinterpret_cast<const float4*>(&a[base]);
    const float4 vr = *reinterpret_cast<const float4*>(&r[base]);
    const float v0 = va.x + vr.x, v1 = va.y + vr.y;
    const float v2 = va.z + vr.z, v3 = va.w + vr.w;

    float sum = v0 + v1 + v2 + v3;
#pragma unroll
    for (int off = 32; off; off >>= 1) sum += __shfl_xor(sum, off);
    const float mean = sum * (1.f / 256.f);

    const float d0 = v0 - mean, d1 = v1 - mean, d2 = v2 - mean, d3 = v3 - mean;
    float ss = d0 * d0 + d1 * d1 + d2 * d2 + d3 * d3;
#pragma unroll
    for (int off = 32; off; off >>= 1) ss += __shfl_xor(ss, off);
    const float rs = rsqrtf(ss * (1.f / 256.f) + 1e-5f);

    const float4 vg = *reinterpret_cast<const float4*>(&g[lane * 4]);
    const float4 vb = *reinterpret_cast<const float4*>(&be[lane * 4]);
    float4 out;
    out.x = d0 * rs * vg.x + vb.x;
    out.y = d1 * rs * vg.y + vb.y;
    out.z = d2 * rs * vg.z + vb.z;
    out.w = d3 * rs * vg.w + vb.w;
    *reinterpret_cast<float4*>(&o[base]) = out;
    if (DUAL) {
        uint2 pk;
        pk.x = (unsigned)f2bf(out.x) | ((unsigned)f2bf(out.y) << 16);
        pk.y = (unsigned)f2bf(out.z) | ((unsigned)f2bf(out.w) << 16);
        *reinterpret_cast<uint2*>(&ob16[base]) = pk;
    }
}

// ---------------------------------------------------------------------------
// One-shot input prep: x fp32->bf16 (blocks 0..4095), weight transposes
// (blocks 4096..5887), QKV bias concat (blocks 5888..5892).
// ---------------------------------------------------------------------------
__global__ void prep_inputs(const float* __restrict__ x,
                            const float* __restrict__ Wq, const float* __restrict__ Wk,
                            const float* __restrict__ Wv, const float* __restrict__ Wo,
                            const float* __restrict__ Wl,
                            const float* __restrict__ bq, const float* __restrict__ bk,
                            const float* __restrict__ bv,
                            u16* __restrict__ xb, u16* __restrict__ wqkvt,
                            u16* __restrict__ wot, u16* __restrict__ wlt,
                            float* __restrict__ bqkv)
{
    const int bid = blockIdx.x, t = threadIdx.x;
    if (bid < 4096) {
        const int i = bid * 256 + t;
        const float4* p = reinterpret_cast<const float4*>(x) + (size_t)i * 2;
        const float4 a = p[0], c = p[1];
        uint4 u;
        u.x = (unsigned)f2bf(a.x) | ((unsigned)f2bf(a.y) << 16);
        u.y = (unsigned)f2bf(a.z) | ((unsigned)f2bf(a.w) << 16);
        u.z = (unsigned)f2bf(c.x) | ((unsigned)f2bf(c.y) << 16);
        u.w = (unsigned)f2bf(c.z) | ((unsigned)f2bf(c.w) << 16);
        *(reinterpret_cast<uint4*>(xb) + i) = u;
    } else if (bid < 4096 + 512) {
        const int n = bid - 4096;
        wqkvt[(size_t)n * 256 + t] = f2bf(Wq[(size_t)t * 512 + n]);
    } else if (bid < 4096 + 1024) {
        const int n = bid - (4096 + 512);
        wqkvt[(size_t)(n + 512) * 256 + t] = f2bf(Wk[(size_t)t * 512 + n]);
    } else if (bid < 4096 + 1280) {
        const int n = bid - (4096 + 1024);
        wqkvt[(size_t)(n + 1024) * 256 + t] = f2bf(Wv[(size_t)t * 256 + n]);
    } else if (bid < 4096 + 1536) {
        const int n = bid - (4096 + 1280);
        wot[(size_t)n * 256 + t] = f2bf(Wo[(size_t)t * 256 + n]);
    } else if (bid < 4096 + 1792) {
        const int n = bid - (4096 + 1536);
        wlt[(size_t)n * 256 + t] = f2bf(Wl[(size_t)t * 256 + n]);
    } else {
        const int i = (bid - (4096 + 1792)) * 256 + t;
        if (i < 1280)
            bqkv[i] = i < 512 ? bq[i] : (i < 1024 ? bk[i - 512] : bv[i - 1024]);
    }
}

// ---------------------------------------------------------------------------
extern "C" void kernel_launch(void* const* d_in, const int* in_sizes, int n_in,
                              void* d_out, int out_size, void* d_ws, size_t ws_size,
                              hipStream_t stream)
{
    const float* x   = (const float*)d_in[0];
    const float* Wq  = (const float*)d_in[1];
    const float* bq  = (const float*)d_in[2];
    const float* Wk  = (const float*)d_in[3];
    const float* bk  = (const float*)d_in[4];
    const float* Wv  = (const float*)d_in[5];
    const float* bv  = (const float*)d_in[6];
    const float* Wo  = (const float*)d_in[7];
    const float* bo  = (const float*)d_in[8];
    const float* rel = (const float*)d_in[9];
    const float* g1  = (const float*)d_in[10];
    const float* b1  = (const float*)d_in[11];
    const float* Wl  = (const float*)d_in[12];
    const float* bl  = (const float*)d_in[13];
    const float* g2  = (const float*)d_in[14];
    const float* b2  = (const float*)d_in[15];
    float* out = (float*)d_out;

    // workspace layout (u16 elements)
    u16* qkvb  = (u16*)d_ws;                        // [32768][1280] bf16 (V cols unused)
    u16* vt    = qkvb  + (size_t)BSROWS * 1280;     // [32][32][8192]
    u16* xb    = vt    + (size_t)BSROWS * 256;      // [32768][256] bf16
    u16* wqkvt = xb    + (size_t)BSROWS * 256;      // [1280][256] bf16
    u16* wot   = wqkvt + 1280 * 256;                // [256][256]
    u16* wlt   = wot   + 256 * 256;                 // [256][256]
    float* bqkv = (float*)(wlt + 256 * 256);        // [1280] fp32

    // fp32 reuse of qkvb region:
    float* tmp = (float*)qkvb;                        // Wo out
    float* xs  = (float*)qkvb + (size_t)BSROWS * 256; // ln1 out fp32
    float* lin = tmp;                                 // Wlin out (tmp dead)
    u16*   xsb   = vt;   // ln1 bf16 (vt dead after attn)
    u16*   attnb = xb;   // attn out bf16 (xb dead after QKV gemm)

    dim3 blk(256);

    prep_inputs<<<4096 + 1792 + 5, blk, 0, stream>>>(
        x, Wq, Wk, Wv, Wo, Wl, bq, bk, bv, xb, wqkvt, wot, wlt, bqkv);

    // fused QKV GEMM: [32768][256] @ [256][1280]; Q,K -> qkvb rows, V -> vt
    gemm_bf16<false, true, true><<<dim3(10 * 256), blk, 0, stream>>>(
        xb, wqkvt, bqkv, qkvb, vt, 1280, 10);

    attn_mfma<<<dim3(S_LEN / 64, NB * NH), blk, 0, stream>>>(qkvb, vt, rel, attnb);

    gemm_bf16<false, false, false><<<dim3(2 * 256), blk, 0, stream>>>(
        attnb, wot, bo, tmp, nullptr, 256, 2);
    add_ln<true><<<dim3(BSROWS / 4), blk, 0, stream>>>(tmp, x, g1, b1, xs, xsb);
    gemm_bf16<true, false, false><<<dim3(2 * 256), blk, 0, stream>>>(
        xsb, wlt, bl, lin, nullptr, 256, 2);
    add_ln<false><<<dim3(BSROWS / 4), blk, 0, stream>>>(lin, xs, g2, b2, out, nullptr);
}

// Round 13
// 232.444 us; speedup vs baseline: 3.4125x; 1.0085x over previous
//
#include <hip/hip_runtime.h>
#include <math.h>

#define S_LEN 8192
#define NB 4
#define NH 8
#define BSROWS (NB * S_LEN)

typedef __bf16 bf16x8 __attribute__((ext_vector_type(8)));
typedef float f32x4 __attribute__((ext_vector_type(4)));
typedef unsigned short u16;
typedef const __attribute__((address_space(1))) void* as1cv;
typedef __attribute__((address_space(3))) void* as3v;

__device__ __forceinline__ u16 f2bf(float f) {
    union { float f; unsigned int u; } v; v.f = f;
    unsigned int r = v.u + 0x7FFFu + ((v.u >> 16) & 1u);
    return (u16)(r >> 16);
}

__device__ __forceinline__ void gload16(const void* g, void* l) {
    __builtin_amdgcn_global_load_lds((as1cv)g, (as3v)l, 16, 0, 0);
}

__device__ __forceinline__ bf16x8 lds_b8(const u16* base, int byteoff) {
    return *reinterpret_cast<const bf16x8*>(reinterpret_cast<const char*>(base) + byteoff);
}

// ---------------------------------------------------------------------------
// Fused QKV GEMM, BM=128 x BN=256 tile (64 MFMA/wave per K-step — 2x the
// MFMA-per-barrier of the 128x128 tile). Grid 1280 = 256 row-panels x 5
// col-panels. Panel cbase==1024 is V: written transposed into vt.
// ---------------------------------------------------------------------------
__global__ __launch_bounds__(256, 2)
void gemm_qkv(const u16* __restrict__ A, const u16* __restrict__ Wt,
              const float* __restrict__ bias, u16* __restrict__ qkvout,
              u16* __restrict__ vtout)
{
    __shared__ u16 As[128 * 64];   // 16 KB
    __shared__ u16 Bs[256 * 64];   // 32 KB

    const int t = threadIdx.x;
    const int wv = t >> 6, ln = t & 63;

    const int qq = gridDim.x >> 3;  // 1280 % 8 == 0
    const int swz = (blockIdx.x & 7) * qq + (blockIdx.x >> 3);
    const int by = swz / 5, bx = swz % 5;
    const int rbase = by * 128, cbase = bx * 256;

    const int wr = wv >> 1, wc = wv & 1;
    const int frow = ln & 15, fk = ln >> 4;

    f32x4 acc[4][8];
#pragma unroll
    for (int i = 0; i < 4; ++i)
#pragma unroll
        for (int j = 0; j < 8; ++j) acc[i][j] = f32x4{0.f, 0.f, 0.f, 0.f};

    const int srow_b = ln >> 3, scb = ln & 7;

    for (int k0 = 0; k0 < 256; k0 += 64) {
#pragma unroll
        for (int r = 0; r < 4; ++r) {
            const int rowA = r * 32 + wv * 8 + srow_b;
            const int cbs = scb ^ (rowA & 7);
            gload16(A + (size_t)(rbase + rowA) * 256 + k0 + cbs * 8,
                    As + r * 2048 + wv * 512);
        }
#pragma unroll
        for (int r = 0; r < 8; ++r) {
            const int rowB = r * 32 + wv * 8 + srow_b;
            const int cbs = scb ^ (rowB & 7);
            gload16(Wt + (size_t)(cbase + rowB) * 256 + k0 + cbs * 8,
                    Bs + r * 2048 + wv * 512);
        }
        __syncthreads();

#pragma unroll
        for (int kk = 0; kk < 2; ++kk) {
            bf16x8 af[4];
#pragma unroll
            for (int mi = 0; mi < 4; ++mi) {
                const int row = wr * 64 + mi * 16 + frow;
                const int cb = (kk * 4 + fk) ^ (row & 7);
                af[mi] = lds_b8(As, row * 128 + cb * 16);
            }
#pragma unroll
            for (int ni = 0; ni < 8; ++ni) {
                const int row = wc * 128 + ni * 16 + frow;
                const int cb = (kk * 4 + fk) ^ (row & 7);
                const bf16x8 bfr = lds_b8(Bs, row * 128 + cb * 16);
#pragma unroll
                for (int mi = 0; mi < 4; ++mi)
                    acc[mi][ni] = __builtin_amdgcn_mfma_f32_16x16x32_bf16(
                        af[mi], bfr, acc[mi][ni], 0, 0, 0);
            }
        }
        __syncthreads();
    }

    float cbias[8];
#pragma unroll
    for (int ni = 0; ni < 8; ++ni)
        cbias[ni] = bias[cbase + wc * 128 + ni * 16 + frow];

    if (cbase == 1024) {
        // V panel -> vt[((b*8+h)*32+dv)][s], 4 consecutive s per uint2 store
#pragma unroll
        for (int mi = 0; mi < 4; ++mi) {
            const int row0 = rbase + wr * 64 + mi * 16 + fk * 4;
            const int b = row0 >> 13, s = row0 & 8191;
#pragma unroll
            for (int ni = 0; ni < 8; ++ni) {
                const int vcol = wc * 128 + ni * 16 + frow;
                const int h = vcol >> 5, dv = vcol & 31;
                uint2 pk;
                pk.x = (unsigned)f2bf(acc[mi][ni][0] + cbias[ni]) |
                       ((unsigned)f2bf(acc[mi][ni][1] + cbias[ni]) << 16);
                pk.y = (unsigned)f2bf(acc[mi][ni][2] + cbias[ni]) |
                       ((unsigned)f2bf(acc[mi][ni][3] + cbias[ni]) << 16);
                *reinterpret_cast<uint2*>(
                    vtout + ((size_t)((b * 8 + h) * 32 + dv)) * S_LEN + s) = pk;
            }
        }
    } else {
#pragma unroll
        for (int mi = 0; mi < 4; ++mi) {
            const int row0 = rbase + wr * 64 + mi * 16 + fk * 4;
#pragma unroll
            for (int ni = 0; ni < 8; ++ni) {
                const int col = cbase + wc * 128 + ni * 16 + frow;
#pragma unroll
                for (int j = 0; j < 4; ++j)
                    qkvout[(size_t)(row0 + j) * 1280 + col] =
                        f2bf(acc[mi][ni][j] + cbias[ni]);
            }
        }
    }
}

// ---------------------------------------------------------------------------
// bf16 MFMA GEMM (BM=BN=128) for the N=256 GEMMs (Wo, Wlin).
// ---------------------------------------------------------------------------
template<bool RELU>
__global__ __launch_bounds__(256, 2)
void gemm_bf16(const u16* __restrict__ A, const u16* __restrict__ Wt,
               const float* __restrict__ bias, float* __restrict__ C,
               int N, int nbx)
{
    __shared__ u16 As[128 * 64];
    __shared__ u16 Bs[128 * 64];

    const int t = threadIdx.x;
    const int wv = t >> 6, ln = t & 63;

    const int qq = gridDim.x >> 3;
    const int swz = (blockIdx.x & 7) * qq + (blockIdx.x >> 3);
    const int by = swz / nbx, bx = swz % nbx;
    const int rbase = by * 128, cbase = bx * 128;

    const int wr = wv >> 1, wc = wv & 1;
    const int frow = ln & 15, fk = ln >> 4;

    f32x4 acc[4][4];
#pragma unroll
    for (int i = 0; i < 4; ++i)
#pragma unroll
        for (int j = 0; j < 4; ++j) acc[i][j] = f32x4{0.f, 0.f, 0.f, 0.f};

    const int srow_b = ln >> 3, scb = ln & 7;

    for (int k0 = 0; k0 < 256; k0 += 64) {
#pragma unroll
        for (int r = 0; r < 4; ++r) {
            const int rowA = r * 32 + wv * 8 + srow_b;
            const int cbs = scb ^ (rowA & 7);
            gload16(A + (size_t)(rbase + rowA) * 256 + k0 + cbs * 8,
                    As + r * 2048 + wv * 512);
            gload16(Wt + (size_t)(cbase + rowA) * 256 + k0 + cbs * 8,
                    Bs + r * 2048 + wv * 512);
        }
        __syncthreads();

        bf16x8 af[4][2], bfr[4][2];
#pragma unroll
        for (int mi = 0; mi < 4; ++mi)
#pragma unroll
            for (int kk = 0; kk < 2; ++kk) {
                const int row = wr * 64 + mi * 16 + frow;
                const int cb = (kk * 4 + fk) ^ (row & 7);
                af[mi][kk] = lds_b8(As, row * 128 + cb * 16);
            }
#pragma unroll
        for (int ni = 0; ni < 4; ++ni)
#pragma unroll
            for (int kk = 0; kk < 2; ++kk) {
                const int row = wc * 64 + ni * 16 + frow;
                const int cb = (kk * 4 + fk) ^ (row & 7);
                bfr[ni][kk] = lds_b8(Bs, row * 128 + cb * 16);
            }
#pragma unroll
        for (int mi = 0; mi < 4; ++mi)
#pragma unroll
            for (int ni = 0; ni < 4; ++ni)
#pragma unroll
                for (int kk = 0; kk < 2; ++kk)
                    acc[mi][ni] = __builtin_amdgcn_mfma_f32_16x16x32_bf16(
                        af[mi][kk], bfr[ni][kk], acc[mi][ni], 0, 0, 0);
        __syncthreads();
    }

    float cbias[4];
#pragma unroll
    for (int ni = 0; ni < 4; ++ni)
        cbias[ni] = bias[cbase + wc * 64 + ni * 16 + frow];

#pragma unroll
    for (int mi = 0; mi < 4; ++mi) {
        const int row0 = rbase + wr * 64 + mi * 16 + fk * 4;
#pragma unroll
        for (int ni = 0; ni < 4; ++ni) {
            const int col = cbase + wc * 64 + ni * 16 + frow;
#pragma unroll
            for (int j = 0; j < 4; ++j) {
                float v = acc[mi][ni][j] + cbias[ni];
                if (RELU) v = fmaxf(v, 0.f);
                C[(size_t)(row0 + j) * N + col] = v;
            }
        }
    }
}

// ---------------------------------------------------------------------------
// MFMA banded attention over the fused QKV buffer [BSROWS][1280] bf16:
// q cols [0,512), k cols [512,1024); V from vt (written by gemm_qkv).
// ---------------------------------------------------------------------------
__global__ __launch_bounds__(256, 3)
void attn_mfma(const u16* __restrict__ qkv, const u16* __restrict__ vt,
               const float* __restrict__ rel, u16* __restrict__ ob)
{
    __shared__ u16 Ks[128 * 64];    // [key][d]  swz ^(key&7)
    __shared__ u16 Qs[64 * 64];     // [q][d]    swz ^(q&7)
    __shared__ u16 Vts[32 * 128];   // [dv][key] swz ^(dv&15)
    __shared__ u16 Ps[4][16 * 104]; // per-wave P[q][key_local], stride 104
    __shared__ float rbs[72];

    const int t = threadIdx.x, wv = t >> 6, ln = t & 63;
    const int bh = blockIdx.y, b = bh >> 3, h = bh & 7;
    const int i0 = blockIdx.x * 64;

#pragma unroll
    for (int r = 0; r < 4; ++r) {
        const int row = r * 32 + wv * 8 + (ln >> 3);
        const int cbs = (ln & 7) ^ (row & 7);
        int pos = i0 - 32 + row;
        pos = pos < 0 ? 0 : (pos >= S_LEN ? S_LEN - 1 : pos);
        const long long grow = (long long)b * S_LEN + pos;
        gload16((const char*)qkv + grow * 2560 + 1024 + h * 128 + cbs * 16,
                Ks + r * 2048 + wv * 512);
    }
#pragma unroll
    for (int r = 0; r < 2; ++r) {
        const int row = r * 32 + wv * 8 + (ln >> 3);
        const int cbs = (ln & 7) ^ (row & 7);
        gload16((const char*)qkv + ((size_t)(b * S_LEN + i0 + row)) * 2560 + h * 128 + cbs * 16,
                Qs + r * 2048 + wv * 512);
    }
#pragma unroll
    for (int r = 0; r < 2; ++r) {
        const int row = r * 16 + wv * 4 + (ln >> 4);
        const int cbs = (ln & 15) ^ (row & 15);
        long long off = (long long)(i0 - 32) * 2 + cbs * 16;
        off = off < 0 ? 0 : (off > (long long)(S_LEN * 2 - 16) ? (long long)(S_LEN * 2 - 16) : off);
        gload16((const char*)vt + ((size_t)bh * 32 + row) * (S_LEN * 2) + off,
                Vts + r * 2048 + wv * 512);
    }
    if (t < 65) rbs[t] = rel[h * 65 + t];
    __syncthreads();

    const int frow = ln & 15, fk = ln >> 4, g = fk;

    bf16x8 aq[2];
    const int qrow = wv * 16 + frow;
#pragma unroll
    for (int kk = 0; kk < 2; ++kk) {
        const int cb = (kk * 4 + fk) ^ (qrow & 7);
        aq[kk] = lds_b8(Qs, qrow * 128 + cb * 16);
    }
    f32x4 sacc[5];
#pragma unroll
    for (int ni = 0; ni < 5; ++ni) {
        sacc[ni] = f32x4{0.f, 0.f, 0.f, 0.f};
        const int krow = wv * 16 + ni * 16 + frow;
#pragma unroll
        for (int kk = 0; kk < 2; ++kk) {
            const int cb = (kk * 4 + fk) ^ (krow & 7);
            bf16x8 bk = lds_b8(Ks, krow * 128 + cb * 16);
            sacc[ni] = __builtin_amdgcn_mfma_f32_16x16x32_bf16(aq[kk], bk, sacc[ni], 0, 0, 0);
        }
    }

    float p[5][4];
#pragma unroll
    for (int j = 0; j < 4; ++j) {
        const int qloc = g * 4 + j;
        const int iq = i0 + wv * 16 + qloc;
        float mx = -1e30f;
#pragma unroll
        for (int ni = 0; ni < 5; ++ni) {
            const int w = ni * 16 + frow - qloc;
            const long long pos = (long long)iq - 32 + w;
            const bool valid = (w >= 0) & (w <= 64) & (pos >= 0) & (pos < S_LEN);
            const int wc2 = w < 0 ? 0 : (w > 64 ? 64 : w);
            const float s = valid ? fmaf(sacc[ni][j], 0.125f, rbs[wc2]) : -1e9f;
            p[ni][j] = s;
            mx = fmaxf(mx, s);
        }
        mx = fmaxf(mx, __shfl_xor(mx, 1));
        mx = fmaxf(mx, __shfl_xor(mx, 2));
        mx = fmaxf(mx, __shfl_xor(mx, 4));
        mx = fmaxf(mx, __shfl_xor(mx, 8));
        float sum = 0.f;
#pragma unroll
        for (int ni = 0; ni < 5; ++ni) {
            const float e = __expf(p[ni][j] - mx);
            p[ni][j] = e; sum += e;
        }
        sum += __shfl_xor(sum, 1);
        sum += __shfl_xor(sum, 2);
        sum += __shfl_xor(sum, 4);
        sum += __shfl_xor(sum, 8);
        const float inv = 1.f / sum;
#pragma unroll
        for (int ni = 0; ni < 5; ++ni) p[ni][j] *= inv;
    }

    u16* Pw = &Ps[wv][0];
    {
        const int zr = ln >> 2, zc = 80 + (ln & 3) * 4;
        *reinterpret_cast<uint2*>(Pw + zr * 104 + zc) = uint2{0u, 0u};
    }
#pragma unroll
    for (int ni = 0; ni < 5; ++ni)
#pragma unroll
        for (int j = 0; j < 4; ++j)
            Pw[(g * 4 + j) * 104 + ni * 16 + frow] = f2bf(p[ni][j]);

    __syncthreads();

    f32x4 oacc[2];
    oacc[0] = f32x4{0.f, 0.f, 0.f, 0.f};
    oacc[1] = f32x4{0.f, 0.f, 0.f, 0.f};
#pragma unroll
    for (int kk = 0; kk < 3; ++kk) {
        bf16x8 bp = lds_b8(Pw, frow * 208 + kk * 64 + fk * 16);
#pragma unroll
        for (int mi = 0; mi < 2; ++mi) {
            const int dv = mi * 16 + frow;
            const int cbv = ((wv * 2 + kk * 4 + fk) & 15) ^ (dv & 15);
            bf16x8 av = lds_b8(Vts, dv * 256 + cbv * 16);
            oacc[mi] = __builtin_amdgcn_mfma_f32_16x16x32_bf16(av, bp, oacc[mi], 0, 0, 0);
        }
    }

    const int iq = i0 + wv * 16 + frow;
#pragma unroll
    for (int mi = 0; mi < 2; ++mi)
#pragma unroll
        for (int j = 0; j < 4; ++j) {
            const int dv = mi * 16 + g * 4 + j;
            ob[((size_t)(b * S_LEN + iq)) * 256 + h * 32 + dv] = f2bf(oacc[mi][j]);
        }
}

// ---------------------------------------------------------------------------
// out = LayerNorm(a + r); optionally also write bf16 copy.
// ---------------------------------------------------------------------------
template<bool DUAL>
__global__ __launch_bounds__(256, 4)
void add_ln(const float* __restrict__ a, const float* __restrict__ r,
            const float* __restrict__ g, const float* __restrict__ be,
            float* __restrict__ o, u16* __restrict__ ob16)
{
    const int row = blockIdx.x * 4 + (threadIdx.x >> 6);
    const int lane = threadIdx.x & 63;
    const size_t base = (size_t)row * 256 + lane * 4;

    const float4 va = *reinterpret_cast<const float4*>(&a[base]);
    const float4 vr = *reinterpret_cast<const float4*>(&r[base]);
    const float v0 = va.x + vr.x, v1 = va.y + vr.y;
    const float v2 = va.z + vr.z, v3 = va.w + vr.w;

    float sum = v0 + v1 + v2 + v3;
#pragma unroll
    for (int off = 32; off; off >>= 1) sum += __shfl_xor(sum, off);
    const float mean = sum * (1.f / 256.f);

    const float d0 = v0 - mean, d1 = v1 - mean, d2 = v2 - mean, d3 = v3 - mean;
    float ss = d0 * d0 + d1 * d1 + d2 * d2 + d3 * d3;
#pragma unroll
    for (int off = 32; off; off >>= 1) ss += __shfl_xor(ss, off);
    const float rs = rsqrtf(ss * (1.f / 256.f) + 1e-5f);

    const float4 vg = *reinterpret_cast<const float4*>(&g[lane * 4]);
    const float4 vb = *reinterpret_cast<const float4*>(&be[lane * 4]);
    float4 out;
    out.x = d0 * rs * vg.x + vb.x;
    out.y = d1 * rs * vg.y + vb.y;
    out.z = d2 * rs * vg.z + vb.z;
    out.w = d3 * rs * vg.w + vb.w;
    *reinterpret_cast<float4*>(&o[base]) = out;
    if (DUAL) {
        uint2 pk;
        pk.x = (unsigned)f2bf(out.x) | ((unsigned)f2bf(out.y) << 16);
        pk.y = (unsigned)f2bf(out.z) | ((unsigned)f2bf(out.w) << 16);
        *reinterpret_cast<uint2*>(&ob16[base]) = pk;
    }
}

// ---------------------------------------------------------------------------
// One-shot input prep: x fp32->bf16 (blocks 0..4095), weight transposes
// (blocks 4096..5887), QKV bias concat (blocks 5888..5892).
// ---------------------------------------------------------------------------
__global__ void prep_inputs(const float* __restrict__ x,
                            const float* __restrict__ Wq, const float* __restrict__ Wk,
                            const float* __restrict__ Wv, const float* __restrict__ Wo,
                            const float* __restrict__ Wl,
                            const float* __restrict__ bq, const float* __restrict__ bk,
                            const float* __restrict__ bv,
                            u16* __restrict__ xb, u16* __restrict__ wqkvt,
                            u16* __restrict__ wot, u16* __restrict__ wlt,
                            float* __restrict__ bqkv)
{
    const int bid = blockIdx.x, t = threadIdx.x;
    if (bid < 4096) {
        const int i = bid * 256 + t;
        const float4* p = reinterpret_cast<const float4*>(x) + (size_t)i * 2;
        const float4 a = p[0], c = p[1];
        uint4 u;
        u.x = (unsigned)f2bf(a.x) | ((unsigned)f2bf(a.y) << 16);
        u.y = (unsigned)f2bf(a.z) | ((unsigned)f2bf(a.w) << 16);
        u.z = (unsigned)f2bf(c.x) | ((unsigned)f2bf(c.y) << 16);
        u.w = (unsigned)f2bf(c.z) | ((unsigned)f2bf(c.w) << 16);
        *(reinterpret_cast<uint4*>(xb) + i) = u;
    } else if (bid < 4096 + 512) {
        const int n = bid - 4096;
        wqkvt[(size_t)n * 256 + t] = f2bf(Wq[(size_t)t * 512 + n]);
    } else if (bid < 4096 + 1024) {
        const int n = bid - (4096 + 512);
        wqkvt[(size_t)(n + 512) * 256 + t] = f2bf(Wk[(size_t)t * 512 + n]);
    } else if (bid < 4096 + 1280) {
        const int n = bid - (4096 + 1024);
        wqkvt[(size_t)(n + 1024) * 256 + t] = f2bf(Wv[(size_t)t * 256 + n]);
    } else if (bid < 4096 + 1536) {
        const int n = bid - (4096 + 1280);
        wot[(size_t)n * 256 + t] = f2bf(Wo[(size_t)t * 256 + n]);
    } else if (bid < 4096 + 1792) {
        const int n = bid - (4096 + 1536);
        wlt[(size_t)n * 256 + t] = f2bf(Wl[(size_t)t * 256 + n]);
    } else {
        const int i = (bid - (4096 + 1792)) * 256 + t;
        if (i < 1280)
            bqkv[i] = i < 512 ? bq[i] : (i < 1024 ? bk[i - 512] : bv[i - 1024]);
    }
}

// ---------------------------------------------------------------------------
extern "C" void kernel_launch(void* const* d_in, const int* in_sizes, int n_in,
                              void* d_out, int out_size, void* d_ws, size_t ws_size,
                              hipStream_t stream)
{
    const float* x   = (const float*)d_in[0];
    const float* Wq  = (const float*)d_in[1];
    const float* bq  = (const float*)d_in[2];
    const float* Wk  = (const float*)d_in[3];
    const float* bk  = (const float*)d_in[4];
    const float* Wv  = (const float*)d_in[5];
    const float* bv  = (const float*)d_in[6];
    const float* Wo  = (const float*)d_in[7];
    const float* bo  = (const float*)d_in[8];
    const float* rel = (const float*)d_in[9];
    const float* g1  = (const float*)d_in[10];
    const float* b1  = (const float*)d_in[11];
    const float* Wl  = (const float*)d_in[12];
    const float* bl  = (const float*)d_in[13];
    const float* g2  = (const float*)d_in[14];
    const float* b2  = (const float*)d_in[15];
    float* out = (float*)d_out;

    // workspace layout (u16 elements)
    u16* qkvb  = (u16*)d_ws;                        // [32768][1280] bf16 (V cols unused)
    u16* vt    = qkvb  + (size_t)BSROWS * 1280;     // [32][32][8192]
    u16* xb    = vt    + (size_t)BSROWS * 256;      // [32768][256] bf16
    u16* wqkvt = xb    + (size_t)BSROWS * 256;      // [1280][256] bf16
    u16* wot   = wqkvt + 1280 * 256;                // [256][256]
    u16* wlt   = wot   + 256 * 256;                 // [256][256]
    float* bqkv = (float*)(wlt + 256 * 256);        // [1280] fp32

    // fp32 reuse of qkvb region:
    float* tmp = (float*)qkvb;                        // Wo out
    float* xs  = (float*)qkvb + (size_t)BSROWS * 256; // ln1 out fp32
    float* lin = tmp;                                 // Wlin out (tmp dead)
    u16*   xsb   = vt;   // ln1 bf16 (vt dead after attn)
    u16*   attnb = xb;   // attn out bf16 (xb dead after QKV gemm)

    dim3 blk(256);

    prep_inputs<<<4096 + 1792 + 5, blk, 0, stream>>>(
        x, Wq, Wk, Wv, Wo, Wl, bq, bk, bv, xb, wqkvt, wot, wlt, bqkv);

    // fused QKV GEMM (BN=256): Q,K -> qkvb rows, V -> vt transposed
    gemm_qkv<<<dim3(5 * 256), blk, 0, stream>>>(xb, wqkvt, bqkv, qkvb, vt);

    attn_mfma<<<dim3(S_LEN / 64, NB * NH), blk, 0, stream>>>(qkvb, vt, rel, attnb);

    gemm_bf16<false><<<dim3(2 * 256), blk, 0, stream>>>(attnb, wot, bo, tmp, 256, 2);
    add_ln<true><<<dim3(BSROWS / 4), blk, 0, stream>>>(tmp, x, g1, b1, xs, xsb);
    gemm_bf16<true><<<dim3(2 * 256), blk, 0, stream>>>(xsb, wlt, bl, lin, 256, 2);
    add_ln<false><<<dim3(BSROWS / 4), blk, 0, stream>>>(lin, xs, g2, b2, out, nullptr);
}